// Round 4
// baseline (4013.860 us; speedup 1.0000x reference)
//
#include <hip/hip_runtime.h>

#define GROUPS 2
#define NUM_VARS 320
#define NVT 640          // GROUPS*NUM_VARS
#define DIM 512
#define VAR_DIM 128
#define NTOK 48000       // B*T
#define TM 32            // tokens per block
#define KC 16            // K-chunk
#define BLOCK 256

// Reorder W[640][512] -> Wq[k/4][640][4] so a K-chunk is one contiguous slab
// and inner-loop float4 LDS reads are consecutive-lane-consecutive-address.
__global__ void make_wq_kernel(const float* __restrict__ W, float* __restrict__ Wq) {
    int f = blockIdx.x * blockDim.x + threadIdx.x;
    if (f >= NVT * DIM) return;
    int kl = f & 3;
    int v  = (f >> 2) % NVT;
    int kq = f / (NVT * 4);
    Wq[f] = W[(size_t)v * DIM + kq * 4 + kl];
}

// amdgpu_waves_per_eu(3,3): R3 showed __launch_bounds__(256,3) only sets the
// occupancy MINIMUM — the allocator still targeted 6 waves/EU (VGPR cap 84 =
// 512/6) and spilled the 80-float accumulator every K-chunk (5 GB scratch
// writes). Pinning min=max=3 forces the 168-VGPR budget. LDS (45.5 KB) caps
// us at 3 blocks/CU regardless, so max=3 costs no occupancy.
template <bool USE_WQ>
__global__ __launch_bounds__(BLOCK)
__attribute__((amdgpu_waves_per_eu(3, 3)))
void vq_main_kernel(const float* __restrict__ x,
                    const float* __restrict__ W,
                    const float* __restrict__ Wq,
                    const float* __restrict__ bias,
                    const float* __restrict__ codebook,
                    float* __restrict__ out,
                    float* __restrict__ avg_out) {
    __shared__ float w_s[KC * NVT];   // layout [kq][v][4]  (40 KB)
    __shared__ float x_s[TM][KC];     // [tok][kk]          (2 KB)
    __shared__ float avg_s[NVT];      // block partial softmax sums

    const int tid = threadIdx.x;
    const int tx  = tid & 63;         // lane
    const int ty  = tid >> 6;         // wave id 0..3
    const int n0  = blockIdx.x * TM;

    float acc[8][10];
#pragma unroll
    for (int t = 0; t < 8; ++t)
#pragma unroll
        for (int j = 0; j < 10; ++j) acc[t][j] = 0.f;

    for (int i = tid; i < NVT; i += BLOCK) avg_s[i] = 0.f;

    for (int k0 = 0; k0 < DIM; k0 += KC) {
        __syncthreads();
        if (USE_WQ) {
            const float4* src = (const float4*)(Wq + (size_t)k0 * NVT);
            float4* dst = (float4*)w_s;
#pragma unroll
            for (int i = 0; i < KC * NVT / 4 / BLOCK; ++i)   // 10 float4 each
                dst[tid + i * BLOCK] = src[tid + i * BLOCK];
        } else {
            // fallback: scratch too small for Wq — strided reads (slow, correct)
            for (int i = tid; i < KC * NVT; i += BLOCK) {
                int kl = i & 3;
                int v  = (i >> 2) % NVT;
                int kq = i / (NVT * 4);
                w_s[i] = W[(size_t)v * DIM + k0 + kq * 4 + kl];
            }
        }
        {
            int tok = tid >> 2, q = tid & 3;
            if (tid < TM * 4)
                *(float4*)&x_s[tok][q * 4] =
                    *(const float4*)(x + (size_t)(n0 + tok) * DIM + k0 + q * 4);
        }
        __syncthreads();

        const float4* w4 = (const float4*)w_s;
        // Two half-passes of 5 vars each: peak live regs ~= acc(80)+wv(20)+misc,
        // comfortably under the 168-VGPR budget (insurance vs partial spill).
#pragma unroll
        for (int kq = 0; kq < KC / 4; ++kq) {
#pragma unroll
            for (int h = 0; h < 2; ++h) {
                float4 wv[5];
#pragma unroll
                for (int j = 0; j < 5; ++j) wv[j] = w4[kq * NVT + tx + 64 * (h * 5 + j)];
#pragma unroll
                for (int t = 0; t < 8; ++t) {
                    float4 xv = *(const float4*)&x_s[ty * 8 + t][kq * 4];
#pragma unroll
                    for (int j = 0; j < 5; ++j) {
                        acc[t][h * 5 + j] = fmaf(xv.x, wv[j].x, acc[t][h * 5 + j]);
                        acc[t][h * 5 + j] = fmaf(xv.y, wv[j].y, acc[t][h * 5 + j]);
                        acc[t][h * 5 + j] = fmaf(xv.z, wv[j].z, acc[t][h * 5 + j]);
                        acc[t][h * 5 + j] = fmaf(xv.w, wv[j].w, acc[t][h * 5 + j]);
                    }
                }
            }
        }
    }

    // bias (zeros in harness, kept for generality)
#pragma unroll
    for (int j = 0; j < 10; ++j) {
        float bv = bias[tx + 64 * j];
#pragma unroll
        for (int t = 0; t < 8; ++t) acc[t][j] += bv;
    }

    // Epilogue: each wave owns 8 tokens (all 640 vars spread over its 64 lanes).
    // MUST be fully unrolled: any runtime index into acc[] demotes it to scratch
    // (rule #20 — R1 measured 19.8 GB of HBM scratch writes from exactly this).
#pragma unroll
    for (int t = 0; t < 8; ++t) {
        const int n = n0 + ty * 8 + t;
#pragma unroll
        for (int g = 0; g < GROUPS; ++g) {
            // local top-2 over this lane's 5 values of group g
            float v1 = -3.4e38f, v2 = -3.4e38f;
            int   i1 = 0x7fffffff, i2 = 0x7fffffff;
#pragma unroll
            for (int jj = 0; jj < 5; ++jj) {
                float val = acc[t][g * 5 + jj];
                int   vv  = tx + 64 * jj;      // index within group
                if ((val > v1) || (val == v1 && vv < i1)) {
                    v2 = v1; i2 = i1; v1 = val; i1 = vv;
                } else if ((val > v2) || (val == v2 && vv < i2)) {
                    v2 = val; i2 = vv;
                }
            }
            // wave butterfly top-2 merge
#pragma unroll
            for (int off = 32; off >= 1; off >>= 1) {
                float o1 = __shfl_xor(v1, off);
                int  oi1 = __shfl_xor(i1, off);
                float o2 = __shfl_xor(v2, off);
                int  oi2 = __shfl_xor(i2, off);
                if ((o1 > v1) || (o1 == v1 && oi1 < i1)) { v2 = v1; i2 = i1; v1 = o1; i1 = oi1; }
                else if ((o1 > v2) || (o1 == v2 && oi1 < i2)) { v2 = o1; i2 = oi1; }
                if ((o2 > v1) || (o2 == v1 && oi2 < i1)) { v2 = v1; i2 = i1; v1 = o2; i1 = oi2; }
                else if ((o2 > v2) || (o2 == v2 && oi2 < i2)) { v2 = o2; i2 = oi2; }
            }

            // softmax (fp32, max = v1)
            float m = v1, s = 0.f;
            float e[5];
#pragma unroll
            for (int jj = 0; jj < 5; ++jj) {
                e[jj] = expf(acc[t][g * 5 + jj] - m);
                s += e[jj];
            }
#pragma unroll
            for (int off = 32; off >= 1; off >>= 1) s += __shfl_xor(s, off);
            float inv = 1.f / s;
#pragma unroll
            for (int jj = 0; jj < 5; ++jj)
                atomicAdd(&avg_s[g * NUM_VARS + tx + 64 * jj], e[jj] * inv);

            // Argmax robustness: fp32 summation-order noise is ~1e-3 while the
            // typical top1-top2 gap is ~6.6 (logits sigma ~22.6). Only when the
            // gap is tiny do we re-verify the two candidates in f64. v1/v2 are
            // wave-uniform after the butterfly -> uniform branch, ~0.8% taken.
            int kbest = i1;
            if (v1 - v2 <= 0.05f) {
                const float* xrow = x + (size_t)n * DIM;
                const float* w1r  = W + (size_t)(g * NUM_VARS + i1) * DIM;
                const float* w2r  = W + (size_t)(g * NUM_VARS + i2) * DIM;
                double d1 = 0.0, d2 = 0.0;
                for (int k = tx; k < DIM; k += 64) {
                    double xv = (double)xrow[k];
                    d1 += xv * (double)w1r[k];
                    d2 += xv * (double)w2r[k];
                }
#pragma unroll
                for (int off = 32; off >= 1; off >>= 1) {
                    d1 += __shfl_xor(d1, off);
                    d2 += __shfl_xor(d2, off);
                }
                d1 += (double)bias[g * NUM_VARS + i1];
                d2 += (double)bias[g * NUM_VARS + i2];
                kbest = (d2 > d1 || (d2 == d1 && i2 < i1)) ? i2 : i1;
            }

            // gather codebook row -> out (float2 per lane, coalesced 512B)
            const float2 cbv = *(const float2*)(codebook +
                                (size_t)(g * NUM_VARS + kbest) * VAR_DIM + 2 * tx);
            *(float2*)(out + (size_t)n * (GROUPS * VAR_DIM) + g * VAR_DIM + 2 * tx) = cbv;
        }
    }

    __syncthreads();
    const float scale = 1.f / (float)NTOK;
    for (int i = tid; i < NVT; i += BLOCK)
        atomicAdd(&avg_out[i], avg_s[i] * scale);
}

extern "C" void kernel_launch(void* const* d_in, const int* in_sizes, int n_in,
                              void* d_out, int out_size, void* d_ws, size_t ws_size,
                              hipStream_t stream) {
    const float* x  = (const float*)d_in[0];
    const float* W  = (const float*)d_in[1];
    const float* b  = (const float*)d_in[2];
    const float* cb = (const float*)d_in[3];
    float* out = (float*)d_out;
    float* avg = out + (size_t)NTOK * GROUPS * VAR_DIM;   // avg_probs tail [2*320]

    hipMemsetAsync(avg, 0, NVT * sizeof(float), stream);

    const size_t wq_bytes = (size_t)NVT * DIM * sizeof(float);
    if (ws_size >= wq_bytes) {
        float* Wq = (float*)d_ws;
        make_wq_kernel<<<(NVT * DIM + 255) / 256, 256, 0, stream>>>(W, Wq);
        vq_main_kernel<true><<<NTOK / TM, BLOCK, 0, stream>>>(x, W, Wq, b, cb, out, avg);
    } else {
        vq_main_kernel<false><<<NTOK / TM, BLOCK, 0, stream>>>(x, W, nullptr, b, cb, out, avg);
    }
}

// Round 5
// 433.978 us; speedup vs baseline: 9.2490x; 9.2490x over previous
//
#include <hip/hip_runtime.h>

#define GROUPS 2
#define NUM_VARS 320
#define NVT 640
#define DIM 512
#define VAR_DIM 128
#define NTOK 48000
#define TM 32            // tokens per block
#define BLOCK 256
#define KCH 256          // K-chunk staged in LDS (2 chunks)
#define XP 264           // padded row stride (ushorts): 264*2B=528B -> +4 banks/row

typedef short bf16x8 __attribute__((ext_vector_type(8)));
typedef float f32x4  __attribute__((ext_vector_type(4)));
typedef unsigned short u16;
typedef u16 u16x4 __attribute__((ext_vector_type(4)));

__device__ inline u16 bf16_rne(float f) {
    unsigned u = __builtin_bit_cast(unsigned, f);
    return (u16)((u + 0x7fffu + ((u >> 16) & 1u)) >> 16);
}
__device__ inline void split2(float f, u16& h, u16& l) {
    h = bf16_rne(f);
    float fh = __builtin_bit_cast(float, (unsigned)h << 16);
    l = bf16_rne(f - fh);
}

// Block: 32 tokens x 320 vars (one group). 4 waves partition vars (80 each =
// 5 col-tiles of 16); tokens shared (2 row-tiles of 16). acc = 10 tiles x 4
// f32 = 40 VGPR/lane. bf16-split GEMM: acc += Ahi*Bhi + Ahi*Blo + Alo*Bhi.
// Fragment layouts (guide 3, m89-verified family):
//   A: row = lane&15, k = 8*(lane>>4)+j  (8 contiguous bf16 -> ds_read_b128)
//   B: col = lane&15, k = 8*(lane>>4)+j  (8 contiguous fp32 from W row -> split)
//   C: col = lane&15, row = 4*(lane>>4)+reg
__global__ __launch_bounds__(BLOCK, 2)
void vq_mfma_kernel(const float* __restrict__ x,
                    const float* __restrict__ W,
                    const float* __restrict__ bias,
                    const float* __restrict__ codebook,
                    float* __restrict__ out,
                    float* __restrict__ avg_out) {
    __shared__ u16 xs_hi[TM][XP];
    __shared__ u16 xs_lo[TM][XP];
    __shared__ float avg_s[NUM_VARS];
    __shared__ float tv_s[TM][4][2];
    __shared__ int   ti_s[TM][4][2];
    __shared__ float m_s[TM], gap_s[TM], sum_s[TM];
    __shared__ int   i1_s[TM], i2_s[TM], kb_s[TM];

    const int tid  = threadIdx.x;
    const int lane = tid & 63;
    const int ty   = tid >> 6;          // wave 0..3
    const int l15  = lane & 15;
    const int l4   = lane >> 4;
    const int g    = blockIdx.x & 1;    // group
    const int n0   = (blockIdx.x >> 1) * TM;

    for (int i = tid; i < NUM_VARS; i += BLOCK) avg_s[i] = 0.f;

    const f32x4 zf = {0.f, 0.f, 0.f, 0.f};
    f32x4 acc[2][5];
#pragma unroll
    for (int rt = 0; rt < 2; ++rt)
#pragma unroll
        for (int ct = 0; ct < 5; ++ct) acc[rt][ct] = zf;

    const int vw = g * NUM_VARS + ty * 80;   // wave's first W row (global)

    for (int c = 0; c < DIM / KCH; ++c) {
        __syncthreads();
        // ---- stage x chunk -> bf16 hi/lo in LDS ----
        {
            const int t  = tid >> 3;            // token 0..31
            const int kb = (tid & 7) * 4;       // 8 threads cover 32 floats
            const float* xp = x + (size_t)(n0 + t) * DIM + c * KCH;
#pragma unroll
            for (int i = 0; i < 8; ++i) {
                const int k = kb + i * 32;
                float4 v = *(const float4*)(xp + k);
                u16x4 hv, lv; u16 h, l;
                split2(v.x, h, l); hv[0] = h; lv[0] = l;
                split2(v.y, h, l); hv[1] = h; lv[1] = l;
                split2(v.z, h, l); hv[2] = h; lv[2] = l;
                split2(v.w, h, l); hv[3] = h; lv[3] = l;
                *(u16x4*)&xs_hi[t][k] = hv;
                *(u16x4*)&xs_lo[t][k] = lv;
            }
        }
        __syncthreads();
        // ---- MFMA over this chunk ----
#pragma unroll
        for (int ks = 0; ks < KCH / 32; ++ks) {
            const int ko = ks * 32 + 8 * l4;
            bf16x8 ah0 = *(const bf16x8*)&xs_hi[l15][ko];
            bf16x8 al0 = *(const bf16x8*)&xs_lo[l15][ko];
            bf16x8 ah1 = *(const bf16x8*)&xs_hi[16 + l15][ko];
            bf16x8 al1 = *(const bf16x8*)&xs_lo[16 + l15][ko];
            const int kg = c * KCH + ks * 32 + 8 * l4;
#pragma unroll
            for (int ct = 0; ct < 5; ++ct) {
                const float* wp = W + (size_t)(vw + ct * 16 + l15) * DIM + kg;
                float4 wa = *(const float4*)wp;
                float4 wb = *(const float4*)(wp + 4);
                bf16x8 bh, bl; u16 h, l;
                split2(wa.x, h, l); bh[0] = (short)h; bl[0] = (short)l;
                split2(wa.y, h, l); bh[1] = (short)h; bl[1] = (short)l;
                split2(wa.z, h, l); bh[2] = (short)h; bl[2] = (short)l;
                split2(wa.w, h, l); bh[3] = (short)h; bl[3] = (short)l;
                split2(wb.x, h, l); bh[4] = (short)h; bl[4] = (short)l;
                split2(wb.y, h, l); bh[5] = (short)h; bl[5] = (short)l;
                split2(wb.z, h, l); bh[6] = (short)h; bl[6] = (short)l;
                split2(wb.w, h, l); bh[7] = (short)h; bl[7] = (short)l;
                acc[0][ct] = __builtin_amdgcn_mfma_f32_16x16x32_bf16(ah0, bh, acc[0][ct], 0, 0, 0);
                acc[0][ct] = __builtin_amdgcn_mfma_f32_16x16x32_bf16(ah0, bl, acc[0][ct], 0, 0, 0);
                acc[0][ct] = __builtin_amdgcn_mfma_f32_16x16x32_bf16(al0, bh, acc[0][ct], 0, 0, 0);
                acc[1][ct] = __builtin_amdgcn_mfma_f32_16x16x32_bf16(ah1, bh, acc[1][ct], 0, 0, 0);
                acc[1][ct] = __builtin_amdgcn_mfma_f32_16x16x32_bf16(ah1, bl, acc[1][ct], 0, 0, 0);
                acc[1][ct] = __builtin_amdgcn_mfma_f32_16x16x32_bf16(al1, bh, acc[1][ct], 0, 0, 0);
            }
        }
    }

    // ---- bias (zeros in harness; kept for generality) ----
#pragma unroll
    for (int ct = 0; ct < 5; ++ct) {
        float bv = bias[vw + ct * 16 + l15];
#pragma unroll
        for (int rt = 0; rt < 2; ++rt)
#pragma unroll
            for (int j = 0; j < 4; ++j) acc[rt][ct][j] += bv;
    }

    // ---- per-token wave-local top-2 (16-lane butterfly), write to LDS ----
#pragma unroll
    for (int rt = 0; rt < 2; ++rt)
#pragma unroll
    for (int j = 0; j < 4; ++j) {
        float v1 = -3.4e38f, v2 = -3.4e38f;
        int   i1 = 0x7fffffff, i2 = 0x7fffffff;
#pragma unroll
        for (int ct = 0; ct < 5; ++ct) {
            float val = acc[rt][ct][j];
            int   vi  = ty * 80 + ct * 16 + l15;
            if ((val > v1) || (val == v1 && vi < i1)) { v2 = v1; i2 = i1; v1 = val; i1 = vi; }
            else if ((val > v2) || (val == v2 && vi < i2)) { v2 = val; i2 = vi; }
        }
#pragma unroll
        for (int off = 1; off <= 8; off <<= 1) {
            float o1 = __shfl_xor(v1, off); int oi1 = __shfl_xor(i1, off);
            float o2 = __shfl_xor(v2, off); int oi2 = __shfl_xor(i2, off);
            if ((o1 > v1) || (o1 == v1 && oi1 < i1)) { v2 = v1; i2 = i1; v1 = o1; i1 = oi1; }
            else if ((o1 > v2) || (o1 == v2 && oi1 < i2)) { v2 = o1; i2 = oi1; }
            if ((o2 > v1) || (o2 == v1 && oi2 < i1)) { v2 = v1; i2 = i1; v1 = o2; i1 = oi2; }
            else if ((o2 > v2) || (o2 == v2 && oi2 < i2)) { v2 = o2; i2 = oi2; }
        }
        if (l15 == 0) {
            const int T = rt * 16 + l4 * 4 + j;
            tv_s[T][ty][0] = v1; tv_s[T][ty][1] = v2;
            ti_s[T][ty][0] = i1; ti_s[T][ty][1] = i2;
        }
    }
    __syncthreads();

    // ---- cross-wave merge (one thread per token) ----
    if (tid < TM) {
        float v1 = -3.4e38f, v2 = -3.4e38f;
        int   i1 = 0x7fffffff, i2 = 0x7fffffff;
#pragma unroll
        for (int w = 0; w < 4; ++w)
#pragma unroll
            for (int q = 0; q < 2; ++q) {
                float val = tv_s[tid][w][q]; int vi = ti_s[tid][w][q];
                if ((val > v1) || (val == v1 && vi < i1)) { v2 = v1; i2 = i1; v1 = val; i1 = vi; }
                else if ((val > v2) || (val == v2 && vi < i2)) { v2 = val; i2 = vi; }
            }
        m_s[tid] = v1; gap_s[tid] = v1 - v2;
        i1_s[tid] = i1; i2_s[tid] = i2; kb_s[tid] = i1; sum_s[tid] = 0.f;
    }
    __syncthreads();

    // ---- softmax: exp + per-token sum ----
#pragma unroll
    for (int rt = 0; rt < 2; ++rt)
#pragma unroll
    for (int j = 0; j < 4; ++j) {
        const int T = rt * 16 + l4 * 4 + j;
        const float m = m_s[T];
        float s = 0.f;
#pragma unroll
        for (int ct = 0; ct < 5; ++ct) {
            float e = expf(acc[rt][ct][j] - m);
            acc[rt][ct][j] = e;
            s += e;
        }
#pragma unroll
        for (int off = 1; off <= 8; off <<= 1) s += __shfl_xor(s, off);
        if (l15 == 0) atomicAdd(&sum_s[T], s);
    }
    __syncthreads();

    // ---- avg_probs partials ----
#pragma unroll
    for (int rt = 0; rt < 2; ++rt)
#pragma unroll
    for (int j = 0; j < 4; ++j) {
        const int T = rt * 16 + l4 * 4 + j;
        const float inv = 1.f / sum_s[T];
#pragma unroll
        for (int ct = 0; ct < 5; ++ct)
            atomicAdd(&avg_s[ty * 80 + ct * 16 + l15], acc[rt][ct][j] * inv);
    }

    // ---- f64 re-verify close argmaxes (bf16x3 logit err ~3e-4 << 0.05 gap) ----
    for (int t8 = 0; t8 < 8; ++t8) {
        const int T = ty * 8 + t8;
        if (gap_s[T] <= 0.05f) {
            const int i1 = i1_s[T], i2 = i2_s[T];
            const float* xr = x + (size_t)(n0 + T) * DIM;
            const float* w1 = W + (size_t)(g * NUM_VARS + i1) * DIM;
            const float* w2 = W + (size_t)(g * NUM_VARS + i2) * DIM;
            double d1 = 0.0, d2 = 0.0;
            for (int k = lane; k < DIM; k += 64) {
                double xv = (double)xr[k];
                d1 += xv * (double)w1[k];
                d2 += xv * (double)w2[k];
            }
#pragma unroll
            for (int off = 1; off <= 32; off <<= 1) {
                d1 += __shfl_xor(d1, off);
                d2 += __shfl_xor(d2, off);
            }
            d1 += (double)bias[g * NUM_VARS + i1];
            d2 += (double)bias[g * NUM_VARS + i2];
            if (lane == 0)
                kb_s[T] = (d2 > d1 || (d2 == d1 && i2 < i1)) ? i2 : i1;
        }
    }
    __syncthreads();

    // ---- codebook gather -> out (coalesced float4) ----
#pragma unroll
    for (int i = 0; i < 4; ++i) {
        const int f = tid + i * BLOCK;
        const int T = f >> 5, p = f & 31;     // 32 float4 per token-half
        const int kb = kb_s[T];
        float4 cv = *(const float4*)(codebook +
                     (size_t)(g * NUM_VARS + kb) * VAR_DIM + p * 4);
        *(float4*)(out + (size_t)(n0 + T) * (GROUPS * VAR_DIM) + g * VAR_DIM + p * 4) = cv;
    }

    const float scale = 1.f / (float)NTOK;
    for (int i = tid; i < NUM_VARS; i += BLOCK)
        atomicAdd(&avg_out[g * NUM_VARS + i], avg_s[i] * scale);
}

extern "C" void kernel_launch(void* const* d_in, const int* in_sizes, int n_in,
                              void* d_out, int out_size, void* d_ws, size_t ws_size,
                              hipStream_t stream) {
    const float* x  = (const float*)d_in[0];
    const float* W  = (const float*)d_in[1];
    const float* b  = (const float*)d_in[2];
    const float* cb = (const float*)d_in[3];
    float* out = (float*)d_out;
    float* avg = out + (size_t)NTOK * GROUPS * VAR_DIM;   // avg_probs tail [640]

    hipMemsetAsync(avg, 0, NVT * sizeof(float), stream);

    vq_mfma_kernel<<<(NTOK / TM) * GROUPS, BLOCK, 0, stream>>>(x, W, b, cb, out, avg);
}

// Round 6
// 317.103 us; speedup vs baseline: 12.6579x; 1.3686x over previous
//
#include <hip/hip_runtime.h>

#define GROUPS 2
#define NUM_VARS 320
#define NVT 640
#define DIM 512
#define VAR_DIM 128
#define NTOK 48000
#define TM 32            // tokens per block
#define BLOCK 256
#define KCH 256          // K-chunk staged in LDS (2 chunks)
#define XP 264           // padded row stride (ushorts)
#define NT16 40          // total 16-var tiles (NVT/16)
#define NKS 16           // total 32-k slices (DIM/32)

typedef short bf16x8 __attribute__((ext_vector_type(8)));
typedef float f32x4  __attribute__((ext_vector_type(4)));
typedef unsigned short u16;
typedef u16 u16x4 __attribute__((ext_vector_type(4)));

__device__ inline u16 bf16_rne(float f) {
    unsigned u = __builtin_bit_cast(unsigned, f);
    return (u16)((u + 0x7fffu + ((u >> 16) & 1u)) >> 16);
}
__device__ inline void split2(float f, u16& h, u16& l) {
    h = bf16_rne(f);
    float fh = __builtin_bit_cast(float, (unsigned)h << 16);
    l = bf16_rne(f - fh);
}

// Pre-split W into bf16 hi/lo in MFMA-fragment order:
//   Wpk[v16][ks][hilo][lane][j], offset = ((v16*16+ks)*2+hilo)*512 + lane*8 + j
// where row = v16*16 + (lane&15), k = ks*32 + 8*(lane>>4) + j.
// Per-lane values are bit-identical to the R5 in-loop split (correctness
// preserved); the main loop's B load becomes one coalesced 16B/lane dwordx4.
__global__ void pack_w_kernel(const float* __restrict__ W, u16* __restrict__ Wpk) {
    int idx = blockIdx.x * blockDim.x + threadIdx.x;
    if (idx >= NT16 * NKS * 64 * 8) return;
    int j    = idx & 7;
    int lane = (idx >> 3) & 63;
    int ks   = (idx >> 9) & 15;
    int v16  = idx >> 13;
    int row  = v16 * 16 + (lane & 15);
    int k    = ks * 32 + 8 * (lane >> 4) + j;
    u16 h, l;
    split2(W[(size_t)row * DIM + k], h, l);
    size_t base = (size_t)((v16 * NKS + ks) * 2) * 512 + lane * 8 + j;
    Wpk[base]       = h;
    Wpk[base + 512] = l;
}

// Block: 32 tokens x 320 vars (one group). 4 waves partition vars (80 each =
// 5 col-tiles of 16); tokens shared (2 row-tiles of 16). acc = 10 tiles x 4
// f32 = 40 VGPR/lane. bf16-split GEMM: acc += Ahi*Bhi + Ahi*Blo + Alo*Bhi.
// Fragment layouts (m89-verified family, end-to-end validated in R5 absmax=0):
//   A: row = lane&15, k = 8*(lane>>4)+j ; B: col = lane&15, same k
//   C: col = lane&15, row = 4*(lane>>4)+reg
template <bool USE_WQ>
__global__ __launch_bounds__(BLOCK, 2)
void vq_mfma_kernel(const float* __restrict__ x,
                    const float* __restrict__ W,
                    const u16* __restrict__ Wpk,
                    const float* __restrict__ bias,
                    const float* __restrict__ codebook,
                    float* __restrict__ out,
                    float* __restrict__ avg_out) {
    __shared__ u16 xs_hi[TM][XP];
    __shared__ u16 xs_lo[TM][XP];
    __shared__ float avg_s[NUM_VARS];
    __shared__ float tv_s[TM][4][2];
    __shared__ int   ti_s[TM][4][2];
    __shared__ float m_s[TM], gap_s[TM], sum_s[TM];
    __shared__ int   i1_s[TM], i2_s[TM], kb_s[TM];

    const int tid  = threadIdx.x;
    const int lane = tid & 63;
    const int ty   = tid >> 6;          // wave 0..3
    const int l15  = lane & 15;
    const int l4   = lane >> 4;
    const int g    = blockIdx.x & 1;    // group
    const int n0   = (blockIdx.x >> 1) * TM;

    for (int i = tid; i < NUM_VARS; i += BLOCK) avg_s[i] = 0.f;

    const f32x4 zf = {0.f, 0.f, 0.f, 0.f};
    f32x4 acc[2][5];
#pragma unroll
    for (int rt = 0; rt < 2; ++rt)
#pragma unroll
        for (int ct = 0; ct < 5; ++ct) acc[rt][ct] = zf;

    const int vw = g * NUM_VARS + ty * 80;   // wave's first W row (global)

    for (int c = 0; c < DIM / KCH; ++c) {
        __syncthreads();
        // ---- stage x chunk -> bf16 hi/lo in LDS ----
        {
            const int t  = tid >> 3;            // token 0..31
            const int kb = (tid & 7) * 4;       // 8 threads cover 32 floats
            const float* xp = x + (size_t)(n0 + t) * DIM + c * KCH;
#pragma unroll
            for (int i = 0; i < 8; ++i) {
                const int k = kb + i * 32;
                float4 v = *(const float4*)(xp + k);
                u16x4 hv, lv; u16 h, l;
                split2(v.x, h, l); hv[0] = h; lv[0] = l;
                split2(v.y, h, l); hv[1] = h; lv[1] = l;
                split2(v.z, h, l); hv[2] = h; lv[2] = l;
                split2(v.w, h, l); hv[3] = h; lv[3] = l;
                *(u16x4*)&xs_hi[t][k] = hv;
                *(u16x4*)&xs_lo[t][k] = lv;
            }
        }
        __syncthreads();
        // ---- MFMA over this chunk ----
#pragma unroll
        for (int ks = 0; ks < KCH / 32; ++ks) {
            const int ko = ks * 32 + 8 * l4;
            bf16x8 ah0 = *(const bf16x8*)&xs_hi[l15][ko];
            bf16x8 al0 = *(const bf16x8*)&xs_lo[l15][ko];
            bf16x8 ah1 = *(const bf16x8*)&xs_hi[16 + l15][ko];
            bf16x8 al1 = *(const bf16x8*)&xs_lo[16 + l15][ko];
            const int ksg = c * (KCH / 32) + ks;
#pragma unroll
            for (int ct = 0; ct < 5; ++ct) {
                bf16x8 bh, bl;
                if (USE_WQ) {
                    const int v16g = g * (NUM_VARS / 16) + ty * 5 + ct;
                    const u16* wp = Wpk + (size_t)((v16g * NKS + ksg) * 2) * 512 + lane * 8;
                    bh = *(const bf16x8*)wp;
                    bl = *(const bf16x8*)(wp + 512);
                } else {
                    const int kg = ksg * 32 + 8 * l4;
                    const float* wp = W + (size_t)(vw + ct * 16 + l15) * DIM + kg;
                    float4 wa = *(const float4*)wp;
                    float4 wb = *(const float4*)(wp + 4);
                    u16 h, l;
                    split2(wa.x, h, l); bh[0] = (short)h; bl[0] = (short)l;
                    split2(wa.y, h, l); bh[1] = (short)h; bl[1] = (short)l;
                    split2(wa.z, h, l); bh[2] = (short)h; bl[2] = (short)l;
                    split2(wa.w, h, l); bh[3] = (short)h; bl[3] = (short)l;
                    split2(wb.x, h, l); bh[4] = (short)h; bl[4] = (short)l;
                    split2(wb.y, h, l); bh[5] = (short)h; bl[5] = (short)l;
                    split2(wb.z, h, l); bh[6] = (short)h; bl[6] = (short)l;
                    split2(wb.w, h, l); bh[7] = (short)h; bl[7] = (short)l;
                }
                acc[0][ct] = __builtin_amdgcn_mfma_f32_16x16x32_bf16(ah0, bh, acc[0][ct], 0, 0, 0);
                acc[0][ct] = __builtin_amdgcn_mfma_f32_16x16x32_bf16(ah0, bl, acc[0][ct], 0, 0, 0);
                acc[0][ct] = __builtin_amdgcn_mfma_f32_16x16x32_bf16(al0, bh, acc[0][ct], 0, 0, 0);
                acc[1][ct] = __builtin_amdgcn_mfma_f32_16x16x32_bf16(ah1, bh, acc[1][ct], 0, 0, 0);
                acc[1][ct] = __builtin_amdgcn_mfma_f32_16x16x32_bf16(ah1, bl, acc[1][ct], 0, 0, 0);
                acc[1][ct] = __builtin_amdgcn_mfma_f32_16x16x32_bf16(al1, bh, acc[1][ct], 0, 0, 0);
            }
        }
    }

    // ---- bias (zeros in harness; kept for generality) ----
#pragma unroll
    for (int ct = 0; ct < 5; ++ct) {
        float bv = bias[vw + ct * 16 + l15];
#pragma unroll
        for (int rt = 0; rt < 2; ++rt)
#pragma unroll
            for (int j = 0; j < 4; ++j) acc[rt][ct][j] += bv;
    }

    // ---- per-token wave-local top-2 (16-lane butterfly), write to LDS ----
#pragma unroll
    for (int rt = 0; rt < 2; ++rt)
#pragma unroll
    for (int j = 0; j < 4; ++j) {
        float v1 = -3.4e38f, v2 = -3.4e38f;
        int   i1 = 0x7fffffff, i2 = 0x7fffffff;
#pragma unroll
        for (int ct = 0; ct < 5; ++ct) {
            float val = acc[rt][ct][j];
            int   vi  = ty * 80 + ct * 16 + l15;
            if ((val > v1) || (val == v1 && vi < i1)) { v2 = v1; i2 = i1; v1 = val; i1 = vi; }
            else if ((val > v2) || (val == v2 && vi < i2)) { v2 = val; i2 = vi; }
        }
#pragma unroll
        for (int off = 1; off <= 8; off <<= 1) {
            float o1 = __shfl_xor(v1, off); int oi1 = __shfl_xor(i1, off);
            float o2 = __shfl_xor(v2, off); int oi2 = __shfl_xor(i2, off);
            if ((o1 > v1) || (o1 == v1 && oi1 < i1)) { v2 = v1; i2 = i1; v1 = o1; i1 = oi1; }
            else if ((o1 > v2) || (o1 == v2 && oi1 < i2)) { v2 = o1; i2 = oi1; }
            if ((o2 > v1) || (o2 == v1 && oi2 < i1)) { v2 = v1; i2 = i1; v1 = o2; i1 = oi2; }
            else if ((o2 > v2) || (o2 == v2 && oi2 < i2)) { v2 = o2; i2 = oi2; }
        }
        if (l15 == 0) {
            const int T = rt * 16 + l4 * 4 + j;
            tv_s[T][ty][0] = v1; tv_s[T][ty][1] = v2;
            ti_s[T][ty][0] = i1; ti_s[T][ty][1] = i2;
        }
    }
    __syncthreads();

    // ---- cross-wave merge (one thread per token) ----
    if (tid < TM) {
        float v1 = -3.4e38f, v2 = -3.4e38f;
        int   i1 = 0x7fffffff, i2 = 0x7fffffff;
#pragma unroll
        for (int w = 0; w < 4; ++w)
#pragma unroll
            for (int q = 0; q < 2; ++q) {
                float val = tv_s[tid][w][q]; int vi = ti_s[tid][w][q];
                if ((val > v1) || (val == v1 && vi < i1)) { v2 = v1; i2 = i1; v1 = val; i1 = vi; }
                else if ((val > v2) || (val == v2 && vi < i2)) { v2 = val; i2 = vi; }
            }
        m_s[tid] = v1; gap_s[tid] = v1 - v2;
        i1_s[tid] = i1; i2_s[tid] = i2; kb_s[tid] = i1; sum_s[tid] = 0.f;
    }
    __syncthreads();

    // ---- softmax: exp + per-token sum ----
#pragma unroll
    for (int rt = 0; rt < 2; ++rt)
#pragma unroll
    for (int j = 0; j < 4; ++j) {
        const int T = rt * 16 + l4 * 4 + j;
        const float m = m_s[T];
        float s = 0.f;
#pragma unroll
        for (int ct = 0; ct < 5; ++ct) {
            float e = expf(acc[rt][ct][j] - m);
            acc[rt][ct][j] = e;
            s += e;
        }
#pragma unroll
        for (int off = 1; off <= 8; off <<= 1) s += __shfl_xor(s, off);
        if (l15 == 0) atomicAdd(&sum_s[T], s);
    }
    __syncthreads();

    // ---- avg_probs partials ----
#pragma unroll
    for (int rt = 0; rt < 2; ++rt)
#pragma unroll
    for (int j = 0; j < 4; ++j) {
        const int T = rt * 16 + l4 * 4 + j;
        const float inv = 1.f / sum_s[T];
#pragma unroll
        for (int ct = 0; ct < 5; ++ct)
            atomicAdd(&avg_s[ty * 80 + ct * 16 + l15], acc[rt][ct][j] * inv);
    }

    // ---- f64 re-verify close argmaxes (bf16x3 logit err ~3e-4 << 0.05 gap) ----
    for (int t8 = 0; t8 < 8; ++t8) {
        const int T = ty * 8 + t8;
        if (gap_s[T] <= 0.05f) {
            const int i1 = i1_s[T], i2 = i2_s[T];
            const float* xr = x + (size_t)(n0 + T) * DIM;
            const float* w1 = W + (size_t)(g * NUM_VARS + i1) * DIM;
            const float* w2 = W + (size_t)(g * NUM_VARS + i2) * DIM;
            double d1 = 0.0, d2 = 0.0;
            for (int k = lane; k < DIM; k += 64) {
                double xv = (double)xr[k];
                d1 += xv * (double)w1[k];
                d2 += xv * (double)w2[k];
            }
#pragma unroll
            for (int off = 1; off <= 32; off <<= 1) {
                d1 += __shfl_xor(d1, off);
                d2 += __shfl_xor(d2, off);
            }
            d1 += (double)bias[g * NUM_VARS + i1];
            d2 += (double)bias[g * NUM_VARS + i2];
            if (lane == 0)
                kb_s[T] = (d2 > d1 || (d2 == d1 && i2 < i1)) ? i2 : i1;
        }
    }
    __syncthreads();

    // ---- codebook gather -> out (coalesced float4) ----
#pragma unroll
    for (int i = 0; i < 4; ++i) {
        const int f = tid + i * BLOCK;
        const int T = f >> 5, p = f & 31;     // 32 float4 per token-half
        const int kb = kb_s[T];
        float4 cv = *(const float4*)(codebook +
                     (size_t)(g * NUM_VARS + kb) * VAR_DIM + p * 4);
        *(float4*)(out + (size_t)(n0 + T) * (GROUPS * VAR_DIM) + g * VAR_DIM + p * 4) = cv;
    }

    const float scale = 1.f / (float)NTOK;
    for (int i = tid; i < NUM_VARS; i += BLOCK)
        atomicAdd(&avg_out[g * NUM_VARS + i], avg_s[i] * scale);
}

extern "C" void kernel_launch(void* const* d_in, const int* in_sizes, int n_in,
                              void* d_out, int out_size, void* d_ws, size_t ws_size,
                              hipStream_t stream) {
    const float* x  = (const float*)d_in[0];
    const float* W  = (const float*)d_in[1];
    const float* b  = (const float*)d_in[2];
    const float* cb = (const float*)d_in[3];
    float* out = (float*)d_out;
    float* avg = out + (size_t)NTOK * GROUPS * VAR_DIM;   // avg_probs tail [640]

    hipMemsetAsync(avg, 0, NVT * sizeof(float), stream);

    const size_t wpk_bytes = (size_t)NT16 * NKS * 2 * 512 * sizeof(u16);  // 1.31 MB
    if (ws_size >= wpk_bytes) {
        u16* Wpk = (u16*)d_ws;
        pack_w_kernel<<<(NT16 * NKS * 64 * 8 + 255) / 256, 256, 0, stream>>>(W, Wpk);
        vq_mfma_kernel<true><<<(NTOK / TM) * GROUPS, BLOCK, 0, stream>>>(x, W, Wpk, b, cb, out, avg);
    } else {
        vq_mfma_kernel<false><<<(NTOK / TM) * GROUPS, BLOCK, 0, stream>>>(x, W, nullptr, b, cb, out, avg);
    }
}

// Round 7
// 217.973 us; speedup vs baseline: 18.4145x; 1.4548x over previous
//
#include <hip/hip_runtime.h>

#define GROUPS 2
#define NUM_VARS 320
#define NVT 640
#define DIM 512
#define VAR_DIM 128
#define NTOK 48000
#define TM 32            // tokens per block
#define BLOCK 256
#define KCH 256          // (fallback path) K-chunk staged in LDS
#define XP 264           // (fallback path) padded row stride (ushorts)
#define NT16 40          // total 16-var tiles (NVT/16)
#define NKS 16           // total 32-k slices (DIM/32)

typedef short bf16x8 __attribute__((ext_vector_type(8)));
typedef float f32x4  __attribute__((ext_vector_type(4)));
typedef unsigned short u16;
typedef u16 u16x4 __attribute__((ext_vector_type(4)));

__device__ inline u16 bf16_rne(float f) {
    unsigned u = __builtin_bit_cast(unsigned, f);
    return (u16)((u + 0x7fffu + ((u >> 16) & 1u)) >> 16);
}
__device__ inline void split2(float f, u16& h, u16& l) {
    h = bf16_rne(f);
    float fh = __builtin_bit_cast(float, (unsigned)h << 16);
    l = bf16_rne(f - fh);
}

// Pre-split W into bf16 hi/lo in MFMA-fragment order (validated R5/R6, absmax=0):
//   offset = ((v16*NKS+ks)*2+hilo)*512 + lane*8 + j
//   row = v16*16 + (lane&15), k = ks*32 + 8*(lane>>4) + j.
__global__ void pack_w_kernel(const float* __restrict__ W, u16* __restrict__ Wpk) {
    int idx = blockIdx.x * blockDim.x + threadIdx.x;
    if (idx >= NT16 * NKS * 64 * 8) return;
    int j    = idx & 7;
    int lane = (idx >> 3) & 63;
    int ks   = (idx >> 9) & 15;
    int v16  = idx >> 13;
    int row  = v16 * 16 + (lane & 15);
    int k    = ks * 32 + 8 * (lane >> 4) + j;
    u16 h, l;
    split2(W[(size_t)row * DIM + k], h, l);
    size_t base = (size_t)((v16 * NKS + ks) * 2) * 512 + lane * 8 + j;
    Wpk[base]       = h;
    Wpk[base + 512] = l;
}

// Pre-split x into bf16 hi/lo row-major planes (memory-bound, ~31 us).
__global__ void split_x_kernel(const float* __restrict__ x,
                               u16* __restrict__ xh, u16* __restrict__ xl) {
    int i = blockIdx.x * blockDim.x + threadIdx.x;   // one float4 per thread
    if (i >= NTOK * DIM / 4) return;
    float4 v = ((const float4*)x)[i];
    u16x4 hv, lv; u16 h, l;
    split2(v.x, h, l); hv[0] = h; lv[0] = l;
    split2(v.y, h, l); hv[1] = h; lv[1] = l;
    split2(v.z, h, l); hv[2] = h; lv[2] = l;
    split2(v.w, h, l); hv[3] = h; lv[3] = l;
    ((u16x4*)xh)[i] = hv;
    ((u16x4*)xl)[i] = lv;
}

// ---------------- fast path: no LDS in main loop, no barriers ----------------
// Block: 32 tokens x one group. 4 waves partition vars (5 col-tiles each);
// A-fragments read straight from the pre-split planes (16 rows x 64B lines,
// L1/L2 served), B from Wpk (1KB/wave coalesced). acc = 40 VGPR.
__global__ __launch_bounds__(BLOCK, 2)
void vq_mfma_reg_kernel(const float* __restrict__ x,
                        const float* __restrict__ W,
                        const u16* __restrict__ xh, const u16* __restrict__ xl,
                        const u16* __restrict__ Wpk,
                        const float* __restrict__ bias,
                        const float* __restrict__ codebook,
                        float* __restrict__ out,
                        float* __restrict__ avg_out) {
    __shared__ float avg_s[NUM_VARS];
    __shared__ float tv_s[TM][4][2];
    __shared__ int   ti_s[TM][4][2];
    __shared__ float m_s[TM], gap_s[TM], sum_s[TM];
    __shared__ int   i1_s[TM], i2_s[TM], kb_s[TM];

    const int tid  = threadIdx.x;
    const int lane = tid & 63;
    const int ty   = tid >> 6;
    const int l15  = lane & 15;
    const int l4   = lane >> 4;
    const int g    = blockIdx.x & 1;
    const int n0   = (blockIdx.x >> 1) * TM;

    for (int i = tid; i < NUM_VARS; i += BLOCK) avg_s[i] = 0.f;

    const f32x4 zf = {0.f, 0.f, 0.f, 0.f};
    f32x4 acc[2][5];
#pragma unroll
    for (int rt = 0; rt < 2; ++rt)
#pragma unroll
        for (int ct = 0; ct < 5; ++ct) acc[rt][ct] = zf;

    const u16* xh_b = xh + (size_t)(n0 + l15) * DIM + 8 * l4;
    const u16* xl_b = xl + (size_t)(n0 + l15) * DIM + 8 * l4;
    const u16* wpk_b = Wpk + (size_t)(g * 20 + ty * 5) * NKS * 2 * 512 + lane * 8;

#pragma unroll 2
    for (int ks = 0; ks < NKS; ++ks) {
        bf16x8 ah0 = *(const bf16x8*)(xh_b + ks * 32);
        bf16x8 al0 = *(const bf16x8*)(xl_b + ks * 32);
        bf16x8 ah1 = *(const bf16x8*)(xh_b + 16 * DIM + ks * 32);
        bf16x8 al1 = *(const bf16x8*)(xl_b + 16 * DIM + ks * 32);
#pragma unroll
        for (int ct = 0; ct < 5; ++ct) {
            const u16* wp = wpk_b + (size_t)(ct * NKS + ks) * 2 * 512;
            bf16x8 bh = *(const bf16x8*)wp;
            bf16x8 bl = *(const bf16x8*)(wp + 512);
            acc[0][ct] = __builtin_amdgcn_mfma_f32_16x16x32_bf16(ah0, bh, acc[0][ct], 0, 0, 0);
            acc[0][ct] = __builtin_amdgcn_mfma_f32_16x16x32_bf16(ah0, bl, acc[0][ct], 0, 0, 0);
            acc[0][ct] = __builtin_amdgcn_mfma_f32_16x16x32_bf16(al0, bh, acc[0][ct], 0, 0, 0);
            acc[1][ct] = __builtin_amdgcn_mfma_f32_16x16x32_bf16(ah1, bh, acc[1][ct], 0, 0, 0);
            acc[1][ct] = __builtin_amdgcn_mfma_f32_16x16x32_bf16(ah1, bl, acc[1][ct], 0, 0, 0);
            acc[1][ct] = __builtin_amdgcn_mfma_f32_16x16x32_bf16(al1, bh, acc[1][ct], 0, 0, 0);
        }
    }

    // bias (zeros in harness; kept for generality)
#pragma unroll
    for (int ct = 0; ct < 5; ++ct) {
        float bv = bias[g * NUM_VARS + ty * 80 + ct * 16 + l15];
#pragma unroll
        for (int rt = 0; rt < 2; ++rt)
#pragma unroll
            for (int j = 0; j < 4; ++j) acc[rt][ct][j] += bv;
    }

    // per-token wave-local top-2 (16-lane butterfly)
#pragma unroll
    for (int rt = 0; rt < 2; ++rt)
#pragma unroll
    for (int j = 0; j < 4; ++j) {
        float v1 = -3.4e38f, v2 = -3.4e38f;
        int   i1 = 0x7fffffff, i2 = 0x7fffffff;
#pragma unroll
        for (int ct = 0; ct < 5; ++ct) {
            float val = acc[rt][ct][j];
            int   vi  = ty * 80 + ct * 16 + l15;
            if ((val > v1) || (val == v1 && vi < i1)) { v2 = v1; i2 = i1; v1 = val; i1 = vi; }
            else if ((val > v2) || (val == v2 && vi < i2)) { v2 = val; i2 = vi; }
        }
#pragma unroll
        for (int off = 1; off <= 8; off <<= 1) {
            float o1 = __shfl_xor(v1, off); int oi1 = __shfl_xor(i1, off);
            float o2 = __shfl_xor(v2, off); int oi2 = __shfl_xor(i2, off);
            if ((o1 > v1) || (o1 == v1 && oi1 < i1)) { v2 = v1; i2 = i1; v1 = o1; i1 = oi1; }
            else if ((o1 > v2) || (o1 == v2 && oi1 < i2)) { v2 = o1; i2 = oi1; }
            if ((o2 > v1) || (o2 == v1 && oi2 < i1)) { v2 = v1; i2 = i1; v1 = o2; i1 = oi2; }
            else if ((o2 > v2) || (o2 == v2 && oi2 < i2)) { v2 = o2; i2 = oi2; }
        }
        if (l15 == 0) {
            const int T = rt * 16 + l4 * 4 + j;
            tv_s[T][ty][0] = v1; tv_s[T][ty][1] = v2;
            ti_s[T][ty][0] = i1; ti_s[T][ty][1] = i2;
        }
    }
    __syncthreads();

    // cross-wave merge (one thread per token)
    if (tid < TM) {
        float v1 = -3.4e38f, v2 = -3.4e38f;
        int   i1 = 0x7fffffff, i2 = 0x7fffffff;
#pragma unroll
        for (int w = 0; w < 4; ++w)
#pragma unroll
            for (int q = 0; q < 2; ++q) {
                float val = tv_s[tid][w][q]; int vi = ti_s[tid][w][q];
                if ((val > v1) || (val == v1 && vi < i1)) { v2 = v1; i2 = i1; v1 = val; i1 = vi; }
                else if ((val > v2) || (val == v2 && vi < i2)) { v2 = val; i2 = vi; }
            }
        m_s[tid] = v1; gap_s[tid] = v1 - v2;
        i1_s[tid] = i1; i2_s[tid] = i2; kb_s[tid] = i1; sum_s[tid] = 0.f;
    }
    __syncthreads();

    // softmax: exp + per-token sum
#pragma unroll
    for (int rt = 0; rt < 2; ++rt)
#pragma unroll
    for (int j = 0; j < 4; ++j) {
        const int T = rt * 16 + l4 * 4 + j;
        const float m = m_s[T];
        float s = 0.f;
#pragma unroll
        for (int ct = 0; ct < 5; ++ct) {
            float e = expf(acc[rt][ct][j] - m);
            acc[rt][ct][j] = e;
            s += e;
        }
#pragma unroll
        for (int off = 1; off <= 8; off <<= 1) s += __shfl_xor(s, off);
        if (l15 == 0) atomicAdd(&sum_s[T], s);
    }
    __syncthreads();

    // avg_probs partials: l4-shuffle reduce (tokens) then per-wave-exclusive
    // plain adds (avg_s[ty*80 .. ty*80+80) touched only by wave ty).
#pragma unroll
    for (int ct = 0; ct < 5; ++ct) {
        float tot = 0.f;
#pragma unroll
        for (int rt = 0; rt < 2; ++rt)
#pragma unroll
        for (int j = 0; j < 4; ++j) {
            const int T = rt * 16 + l4 * 4 + j;
            float v = acc[rt][ct][j] / sum_s[T];
            v += __shfl_xor(v, 16);
            v += __shfl_xor(v, 32);
            tot += v;
        }
        if (l4 == 0) avg_s[ty * 80 + ct * 16 + l15] += tot;
    }

    // f64 re-verify close argmaxes (bf16x3 logit err ~3e-4 << 0.05 gap)
    for (int t8 = 0; t8 < 8; ++t8) {
        const int T = ty * 8 + t8;
        if (gap_s[T] <= 0.05f) {
            const int i1 = i1_s[T], i2 = i2_s[T];
            const float* xr = x + (size_t)(n0 + T) * DIM;
            const float* w1 = W + (size_t)(g * NUM_VARS + i1) * DIM;
            const float* w2 = W + (size_t)(g * NUM_VARS + i2) * DIM;
            double d1 = 0.0, d2 = 0.0;
            for (int k = lane; k < DIM; k += 64) {
                double xv = (double)xr[k];
                d1 += xv * (double)w1[k];
                d2 += xv * (double)w2[k];
            }
#pragma unroll
            for (int off = 1; off <= 32; off <<= 1) {
                d1 += __shfl_xor(d1, off);
                d2 += __shfl_xor(d2, off);
            }
            d1 += (double)bias[g * NUM_VARS + i1];
            d2 += (double)bias[g * NUM_VARS + i2];
            if (lane == 0)
                kb_s[T] = (d2 > d1 || (d2 == d1 && i2 < i1)) ? i2 : i1;
        }
    }
    __syncthreads();

    // codebook gather -> out (coalesced float4)
#pragma unroll
    for (int i = 0; i < 4; ++i) {
        const int f = tid + i * BLOCK;
        const int T = f >> 5, p = f & 31;
        const int kb = kb_s[T];
        float4 cv = *(const float4*)(codebook +
                     (size_t)(g * NUM_VARS + kb) * VAR_DIM + p * 4);
        *(float4*)(out + (size_t)(n0 + T) * (GROUPS * VAR_DIM) + g * VAR_DIM + p * 4) = cv;
    }

    const float scale = 1.f / (float)NTOK;
    for (int i = tid; i < NUM_VARS; i += BLOCK)
        atomicAdd(&avg_out[g * NUM_VARS + i], avg_s[i] * scale);
}

// ---------------- fallback path (R6, proven): LDS-staged x ----------------
template <bool USE_WQ>
__global__ __launch_bounds__(BLOCK, 2)
void vq_mfma_kernel(const float* __restrict__ x,
                    const float* __restrict__ W,
                    const u16* __restrict__ Wpk,
                    const float* __restrict__ bias,
                    const float* __restrict__ codebook,
                    float* __restrict__ out,
                    float* __restrict__ avg_out) {
    __shared__ u16 xs_hi[TM][XP];
    __shared__ u16 xs_lo[TM][XP];
    __shared__ float avg_s[NUM_VARS];
    __shared__ float tv_s[TM][4][2];
    __shared__ int   ti_s[TM][4][2];
    __shared__ float m_s[TM], gap_s[TM], sum_s[TM];
    __shared__ int   i1_s[TM], i2_s[TM], kb_s[TM];

    const int tid  = threadIdx.x;
    const int lane = tid & 63;
    const int ty   = tid >> 6;
    const int l15  = lane & 15;
    const int l4   = lane >> 4;
    const int g    = blockIdx.x & 1;
    const int n0   = (blockIdx.x >> 1) * TM;

    for (int i = tid; i < NUM_VARS; i += BLOCK) avg_s[i] = 0.f;

    const f32x4 zf = {0.f, 0.f, 0.f, 0.f};
    f32x4 acc[2][5];
#pragma unroll
    for (int rt = 0; rt < 2; ++rt)
#pragma unroll
        for (int ct = 0; ct < 5; ++ct) acc[rt][ct] = zf;

    const int vw = g * NUM_VARS + ty * 80;

    for (int c = 0; c < DIM / KCH; ++c) {
        __syncthreads();
        {
            const int t  = tid >> 3;
            const int kb = (tid & 7) * 4;
            const float* xp = x + (size_t)(n0 + t) * DIM + c * KCH;
#pragma unroll
            for (int i = 0; i < 8; ++i) {
                const int k = kb + i * 32;
                float4 v = *(const float4*)(xp + k);
                u16x4 hv, lv; u16 h, l;
                split2(v.x, h, l); hv[0] = h; lv[0] = l;
                split2(v.y, h, l); hv[1] = h; lv[1] = l;
                split2(v.z, h, l); hv[2] = h; lv[2] = l;
                split2(v.w, h, l); hv[3] = h; lv[3] = l;
                *(u16x4*)&xs_hi[t][k] = hv;
                *(u16x4*)&xs_lo[t][k] = lv;
            }
        }
        __syncthreads();
#pragma unroll
        for (int ks = 0; ks < KCH / 32; ++ks) {
            const int ko = ks * 32 + 8 * l4;
            bf16x8 ah0 = *(const bf16x8*)&xs_hi[l15][ko];
            bf16x8 al0 = *(const bf16x8*)&xs_lo[l15][ko];
            bf16x8 ah1 = *(const bf16x8*)&xs_hi[16 + l15][ko];
            bf16x8 al1 = *(const bf16x8*)&xs_lo[16 + l15][ko];
            const int ksg = c * (KCH / 32) + ks;
#pragma unroll
            for (int ct = 0; ct < 5; ++ct) {
                bf16x8 bh, bl;
                if (USE_WQ) {
                    const int v16g = g * (NUM_VARS / 16) + ty * 5 + ct;
                    const u16* wp = Wpk + (size_t)((v16g * NKS + ksg) * 2) * 512 + lane * 8;
                    bh = *(const bf16x8*)wp;
                    bl = *(const bf16x8*)(wp + 512);
                } else {
                    const int kg = ksg * 32 + 8 * l4;
                    const float* wp = W + (size_t)(vw + ct * 16 + l15) * DIM + kg;
                    float4 wa = *(const float4*)wp;
                    float4 wb = *(const float4*)(wp + 4);
                    u16 h, l;
                    split2(wa.x, h, l); bh[0] = (short)h; bl[0] = (short)l;
                    split2(wa.y, h, l); bh[1] = (short)h; bl[1] = (short)l;
                    split2(wa.z, h, l); bh[2] = (short)h; bl[2] = (short)l;
                    split2(wa.w, h, l); bh[3] = (short)h; bl[3] = (short)l;
                    split2(wb.x, h, l); bh[4] = (short)h; bl[4] = (short)l;
                    split2(wb.y, h, l); bh[5] = (short)h; bl[5] = (short)l;
                    split2(wb.z, h, l); bh[6] = (short)h; bl[6] = (short)l;
                    split2(wb.w, h, l); bh[7] = (short)h; bl[7] = (short)l;
                }
                acc[0][ct] = __builtin_amdgcn_mfma_f32_16x16x32_bf16(ah0, bh, acc[0][ct], 0, 0, 0);
                acc[0][ct] = __builtin_amdgcn_mfma_f32_16x16x32_bf16(ah0, bl, acc[0][ct], 0, 0, 0);
                acc[0][ct] = __builtin_amdgcn_mfma_f32_16x16x32_bf16(al0, bh, acc[0][ct], 0, 0, 0);
                acc[1][ct] = __builtin_amdgcn_mfma_f32_16x16x32_bf16(ah1, bh, acc[1][ct], 0, 0, 0);
                acc[1][ct] = __builtin_amdgcn_mfma_f32_16x16x32_bf16(ah1, bl, acc[1][ct], 0, 0, 0);
                acc[1][ct] = __builtin_amdgcn_mfma_f32_16x16x32_bf16(al1, bh, acc[1][ct], 0, 0, 0);
            }
        }
    }

#pragma unroll
    for (int ct = 0; ct < 5; ++ct) {
        float bv = bias[vw + ct * 16 + l15];
#pragma unroll
        for (int rt = 0; rt < 2; ++rt)
#pragma unroll
            for (int j = 0; j < 4; ++j) acc[rt][ct][j] += bv;
    }

#pragma unroll
    for (int rt = 0; rt < 2; ++rt)
#pragma unroll
    for (int j = 0; j < 4; ++j) {
        float v1 = -3.4e38f, v2 = -3.4e38f;
        int   i1 = 0x7fffffff, i2 = 0x7fffffff;
#pragma unroll
        for (int ct = 0; ct < 5; ++ct) {
            float val = acc[rt][ct][j];
            int   vi  = ty * 80 + ct * 16 + l15;
            if ((val > v1) || (val == v1 && vi < i1)) { v2 = v1; i2 = i1; v1 = val; i1 = vi; }
            else if ((val > v2) || (val == v2 && vi < i2)) { v2 = val; i2 = vi; }
        }
#pragma unroll
        for (int off = 1; off <= 8; off <<= 1) {
            float o1 = __shfl_xor(v1, off); int oi1 = __shfl_xor(i1, off);
            float o2 = __shfl_xor(v2, off); int oi2 = __shfl_xor(i2, off);
            if ((o1 > v1) || (o1 == v1 && oi1 < i1)) { v2 = v1; i2 = i1; v1 = o1; i1 = oi1; }
            else if ((o1 > v2) || (o1 == v2 && oi1 < i2)) { v2 = o1; i2 = oi1; }
            if ((o2 > v1) || (o2 == v1 && oi2 < i1)) { v2 = v1; i2 = i1; v1 = o2; i1 = oi2; }
            else if ((o2 > v2) || (o2 == v2 && oi2 < i2)) { v2 = o2; i2 = oi2; }
        }
        if (l15 == 0) {
            const int T = rt * 16 + l4 * 4 + j;
            tv_s[T][ty][0] = v1; tv_s[T][ty][1] = v2;
            ti_s[T][ty][0] = i1; ti_s[T][ty][1] = i2;
        }
    }
    __syncthreads();

    if (tid < TM) {
        float v1 = -3.4e38f, v2 = -3.4e38f;
        int   i1 = 0x7fffffff, i2 = 0x7fffffff;
#pragma unroll
        for (int w = 0; w < 4; ++w)
#pragma unroll
            for (int q = 0; q < 2; ++q) {
                float val = tv_s[tid][w][q]; int vi = ti_s[tid][w][q];
                if ((val > v1) || (val == v1 && vi < i1)) { v2 = v1; i2 = i1; v1 = val; i1 = vi; }
                else if ((val > v2) || (val == v2 && vi < i2)) { v2 = val; i2 = vi; }
            }
        m_s[tid] = v1; gap_s[tid] = v1 - v2;
        i1_s[tid] = i1; i2_s[tid] = i2; kb_s[tid] = i1; sum_s[tid] = 0.f;
    }
    __syncthreads();

#pragma unroll
    for (int rt = 0; rt < 2; ++rt)
#pragma unroll
    for (int j = 0; j < 4; ++j) {
        const int T = rt * 16 + l4 * 4 + j;
        const float m = m_s[T];
        float s = 0.f;
#pragma unroll
        for (int ct = 0; ct < 5; ++ct) {
            float e = expf(acc[rt][ct][j] - m);
            acc[rt][ct][j] = e;
            s += e;
        }
#pragma unroll
        for (int off = 1; off <= 8; off <<= 1) s += __shfl_xor(s, off);
        if (l15 == 0) atomicAdd(&sum_s[T], s);
    }
    __syncthreads();

#pragma unroll
    for (int ct = 0; ct < 5; ++ct) {
        float tot = 0.f;
#pragma unroll
        for (int rt = 0; rt < 2; ++rt)
#pragma unroll
        for (int j = 0; j < 4; ++j) {
            const int T = rt * 16 + l4 * 4 + j;
            float v = acc[rt][ct][j] / sum_s[T];
            v += __shfl_xor(v, 16);
            v += __shfl_xor(v, 32);
            tot += v;
        }
        if (l4 == 0) avg_s[ty * 80 + ct * 16 + l15] += tot;
    }

    for (int t8 = 0; t8 < 8; ++t8) {
        const int T = ty * 8 + t8;
        if (gap_s[T] <= 0.05f) {
            const int i1 = i1_s[T], i2 = i2_s[T];
            const float* xr = x + (size_t)(n0 + T) * DIM;
            const float* w1 = W + (size_t)(g * NUM_VARS + i1) * DIM;
            const float* w2 = W + (size_t)(g * NUM_VARS + i2) * DIM;
            double d1 = 0.0, d2 = 0.0;
            for (int k = lane; k < DIM; k += 64) {
                double xv = (double)xr[k];
                d1 += xv * (double)w1[k];
                d2 += xv * (double)w2[k];
            }
#pragma unroll
            for (int off = 1; off <= 32; off <<= 1) {
                d1 += __shfl_xor(d1, off);
                d2 += __shfl_xor(d2, off);
            }
            d1 += (double)bias[g * NUM_VARS + i1];
            d2 += (double)bias[g * NUM_VARS + i2];
            if (lane == 0)
                kb_s[T] = (d2 > d1 || (d2 == d1 && i2 < i1)) ? i2 : i1;
        }
    }
    __syncthreads();

#pragma unroll
    for (int i = 0; i < 4; ++i) {
        const int f = tid + i * BLOCK;
        const int T = f >> 5, p = f & 31;
        const int kb = kb_s[T];
        float4 cv = *(const float4*)(codebook +
                     (size_t)(g * NUM_VARS + kb) * VAR_DIM + p * 4);
        *(float4*)(out + (size_t)(n0 + T) * (GROUPS * VAR_DIM) + g * VAR_DIM + p * 4) = cv;
    }

    const float scale = 1.f / (float)NTOK;
    for (int i = tid; i < NUM_VARS; i += BLOCK)
        atomicAdd(&avg_out[g * NUM_VARS + i], avg_s[i] * scale);
}

extern "C" void kernel_launch(void* const* d_in, const int* in_sizes, int n_in,
                              void* d_out, int out_size, void* d_ws, size_t ws_size,
                              hipStream_t stream) {
    const float* x  = (const float*)d_in[0];
    const float* W  = (const float*)d_in[1];
    const float* b  = (const float*)d_in[2];
    const float* cb = (const float*)d_in[3];
    float* out = (float*)d_out;
    float* avg = out + (size_t)NTOK * GROUPS * VAR_DIM;

    hipMemsetAsync(avg, 0, NVT * sizeof(float), stream);

    const size_t wpk_bytes   = (size_t)NT16 * NKS * 2 * 512 * sizeof(u16);      // 1.31 MB
    const size_t plane_bytes = (size_t)NTOK * DIM * sizeof(u16);                // 49.2 MB
    const size_t full_bytes  = wpk_bytes + 2 * plane_bytes;                     // 99.7 MB

    if (ws_size >= full_bytes) {
        u16* Wpk = (u16*)d_ws;
        u16* xh  = (u16*)((char*)d_ws + wpk_bytes);
        u16* xl  = xh + (size_t)NTOK * DIM;
        pack_w_kernel<<<(NT16 * NKS * 64 * 8 + 255) / 256, 256, 0, stream>>>(W, Wpk);
        split_x_kernel<<<(NTOK * DIM / 4 + 255) / 256, 256, 0, stream>>>(x, xh, xl);
        vq_mfma_reg_kernel<<<(NTOK / TM) * GROUPS, BLOCK, 0, stream>>>(
            x, W, xh, xl, Wpk, b, cb, out, avg);
    } else if (ws_size >= wpk_bytes) {
        u16* Wpk = (u16*)d_ws;
        pack_w_kernel<<<(NT16 * NKS * 64 * 8 + 255) / 256, 256, 0, stream>>>(W, Wpk);
        vq_mfma_kernel<true><<<(NTOK / TM) * GROUPS, BLOCK, 0, stream>>>(x, W, Wpk, b, cb, out, avg);
    } else {
        vq_mfma_kernel<false><<<(NTOK / TM) * GROUPS, BLOCK, 0, stream>>>(x, W, nullptr, b, cb, out, avg);
    }
}

// Round 8
// 204.405 us; speedup vs baseline: 19.6368x; 1.0664x over previous
//
#include <hip/hip_runtime.h>

#define GROUPS 2
#define NUM_VARS 320
#define NVT 640
#define DIM 512
#define VAR_DIM 128
#define NTOK 48000
#define TM 32            // tokens per block
#define BLOCK 256
#define KCH 256          // (fallback path) K-chunk staged in LDS
#define XP 264           // (fallback path) padded row stride (ushorts)
#define NT16 40          // total 16-var tiles (NVT/16)
#define NKS 16           // total 32-k slices (DIM/32)
#define NTILE (NTOK / 16)   // 3000 16-token tiles

typedef short bf16x8 __attribute__((ext_vector_type(8)));
typedef float f32x4  __attribute__((ext_vector_type(4)));
typedef unsigned short u16;
typedef u16 u16x4 __attribute__((ext_vector_type(4)));
typedef u16 u16x8 __attribute__((ext_vector_type(8)));

__device__ inline u16 bf16_rne(float f) {
    unsigned u = __builtin_bit_cast(unsigned, f);
    return (u16)((u + 0x7fffu + ((u >> 16) & 1u)) >> 16);
}
__device__ inline void split2(float f, u16& h, u16& l) {
    h = bf16_rne(f);
    float fh = __builtin_bit_cast(float, (unsigned)h << 16);
    l = bf16_rne(f - fh);
}

// Pre-split W into bf16 hi/lo in MFMA-fragment order (validated R5-R7, absmax=0):
//   offset = ((v16*NKS+ks)*2+hilo)*512 + lane*8 + j
//   row = v16*16 + (lane&15), k = ks*32 + 8*(lane>>4) + j.
__global__ void pack_w_kernel(const float* __restrict__ W, u16* __restrict__ Wpk) {
    int idx = blockIdx.x * blockDim.x + threadIdx.x;
    if (idx >= NT16 * NKS * 64 * 8) return;
    int j    = idx & 7;
    int lane = (idx >> 3) & 63;
    int ks   = (idx >> 9) & 15;
    int v16  = idx >> 13;
    int row  = v16 * 16 + (lane & 15);
    int k    = ks * 32 + 8 * (lane >> 4) + j;
    u16 h, l;
    split2(W[(size_t)row * DIM + k], h, l);
    size_t base = (size_t)((v16 * NKS + ks) * 2) * 512 + lane * 8 + j;
    Wpk[base]       = h;
    Wpk[base + 512] = l;
}

// Pre-split x into bf16 hi/lo in MFMA A-fragment order:
//   xpk[tile][ks][hilo][512]: offset = ((tile*16+ks)*2+hilo)*512 + lane*8 + j
//   token = tile*16 + (lane&15), k = ks*32 + 8*(lane>>4) + j.
// R7's row-major planes made every main-loop A-load touch 16 scattered 64B
// lines (16 token rows) -> ~800 GB/s effective HBM, latency-bound. Packed
// order makes the A-load one contiguous 1KB dwordx4 per wave, like B.
__global__ void split_x_pack_kernel(const float* __restrict__ x,
                                    u16* __restrict__ xpk) {
    const int gw   = (blockIdx.x * blockDim.x + threadIdx.x) >> 6;  // wave = tile
    const int lane = threadIdx.x & 63;
    if (gw >= NTILE) return;
    const int l15 = lane & 15, l4 = lane >> 4;
    const float* xr = x + (size_t)(gw * 16 + l15) * DIM + 8 * l4;
    u16* dst = xpk + (size_t)gw * (NKS * 2 * 512) + lane * 8;
#pragma unroll 4
    for (int ks = 0; ks < NKS; ++ks) {
        float4 a = *(const float4*)(xr + ks * 32);
        float4 b = *(const float4*)(xr + ks * 32 + 4);
        u16x8 hv, lv; u16 h, l;
        split2(a.x, h, l); hv[0] = h; lv[0] = l;
        split2(a.y, h, l); hv[1] = h; lv[1] = l;
        split2(a.z, h, l); hv[2] = h; lv[2] = l;
        split2(a.w, h, l); hv[3] = h; lv[3] = l;
        split2(b.x, h, l); hv[4] = h; lv[4] = l;
        split2(b.y, h, l); hv[5] = h; lv[5] = l;
        split2(b.z, h, l); hv[6] = h; lv[6] = l;
        split2(b.w, h, l); hv[7] = h; lv[7] = l;
        *(u16x8*)(dst + ks * 1024)       = hv;
        *(u16x8*)(dst + ks * 1024 + 512) = lv;
    }
}

// ---------------- fast path: all loads contiguous 1KB/wave, no LDS/barriers --
// Block: 32 tokens x one group. 4 waves partition vars (5 col-tiles each).
// Per ks: 4 A-loads (2 tiles x hi/lo) + 10 B-loads, all wave-contiguous
// dwordx4, then 30 MFMAs. acc = 40 VGPR.
__global__ __launch_bounds__(BLOCK, 2)
void vq_mfma_reg_kernel(const float* __restrict__ x,
                        const float* __restrict__ W,
                        const u16* __restrict__ xpk,
                        const u16* __restrict__ Wpk,
                        const float* __restrict__ bias,
                        const float* __restrict__ codebook,
                        float* __restrict__ out,
                        float* __restrict__ avg_out) {
    __shared__ float avg_s[NUM_VARS];
    __shared__ float tv_s[TM][4][2];
    __shared__ int   ti_s[TM][4][2];
    __shared__ float m_s[TM], gap_s[TM], sum_s[TM];
    __shared__ int   i1_s[TM], i2_s[TM], kb_s[TM];

    const int tid  = threadIdx.x;
    const int lane = tid & 63;
    const int ty   = tid >> 6;
    const int l15  = lane & 15;
    const int l4   = lane >> 4;
    const int g    = blockIdx.x & 1;
    const int n0   = (blockIdx.x >> 1) * TM;

    for (int i = tid; i < NUM_VARS; i += BLOCK) avg_s[i] = 0.f;

    const f32x4 zf = {0.f, 0.f, 0.f, 0.f};
    f32x4 acc[2][5];
#pragma unroll
    for (int rt = 0; rt < 2; ++rt)
#pragma unroll
        for (int ct = 0; ct < 5; ++ct) acc[rt][ct] = zf;

    const u16* xa0 = xpk + (size_t)((blockIdx.x >> 1) * 2) * (NKS * 2 * 512) + lane * 8;
    const u16* xa1 = xa0 + NKS * 2 * 512;
    const u16* wpk_b = Wpk + (size_t)(g * 20 + ty * 5) * NKS * 2 * 512 + lane * 8;

#pragma unroll 4
    for (int ks = 0; ks < NKS; ++ks) {
        bf16x8 ah0 = *(const bf16x8*)(xa0 + ks * 1024);
        bf16x8 al0 = *(const bf16x8*)(xa0 + ks * 1024 + 512);
        bf16x8 ah1 = *(const bf16x8*)(xa1 + ks * 1024);
        bf16x8 al1 = *(const bf16x8*)(xa1 + ks * 1024 + 512);
#pragma unroll
        for (int ct = 0; ct < 5; ++ct) {
            const u16* wp = wpk_b + (size_t)(ct * NKS + ks) * 2 * 512;
            bf16x8 bh = *(const bf16x8*)wp;
            bf16x8 bl = *(const bf16x8*)(wp + 512);
            acc[0][ct] = __builtin_amdgcn_mfma_f32_16x16x32_bf16(ah0, bh, acc[0][ct], 0, 0, 0);
            acc[0][ct] = __builtin_amdgcn_mfma_f32_16x16x32_bf16(ah0, bl, acc[0][ct], 0, 0, 0);
            acc[0][ct] = __builtin_amdgcn_mfma_f32_16x16x32_bf16(al0, bh, acc[0][ct], 0, 0, 0);
            acc[1][ct] = __builtin_amdgcn_mfma_f32_16x16x32_bf16(ah1, bh, acc[1][ct], 0, 0, 0);
            acc[1][ct] = __builtin_amdgcn_mfma_f32_16x16x32_bf16(ah1, bl, acc[1][ct], 0, 0, 0);
            acc[1][ct] = __builtin_amdgcn_mfma_f32_16x16x32_bf16(al1, bh, acc[1][ct], 0, 0, 0);
        }
    }

    // bias (zeros in harness; kept for generality)
#pragma unroll
    for (int ct = 0; ct < 5; ++ct) {
        float bv = bias[g * NUM_VARS + ty * 80 + ct * 16 + l15];
#pragma unroll
        for (int rt = 0; rt < 2; ++rt)
#pragma unroll
            for (int j = 0; j < 4; ++j) acc[rt][ct][j] += bv;
    }

    // per-token wave-local top-2 (16-lane butterfly)
#pragma unroll
    for (int rt = 0; rt < 2; ++rt)
#pragma unroll
    for (int j = 0; j < 4; ++j) {
        float v1 = -3.4e38f, v2 = -3.4e38f;
        int   i1 = 0x7fffffff, i2 = 0x7fffffff;
#pragma unroll
        for (int ct = 0; ct < 5; ++ct) {
            float val = acc[rt][ct][j];
            int   vi  = ty * 80 + ct * 16 + l15;
            if ((val > v1) || (val == v1 && vi < i1)) { v2 = v1; i2 = i1; v1 = val; i1 = vi; }
            else if ((val > v2) || (val == v2 && vi < i2)) { v2 = val; i2 = vi; }
        }
#pragma unroll
        for (int off = 1; off <= 8; off <<= 1) {
            float o1 = __shfl_xor(v1, off); int oi1 = __shfl_xor(i1, off);
            float o2 = __shfl_xor(v2, off); int oi2 = __shfl_xor(i2, off);
            if ((o1 > v1) || (o1 == v1 && oi1 < i1)) { v2 = v1; i2 = i1; v1 = o1; i1 = oi1; }
            else if ((o1 > v2) || (o1 == v2 && oi1 < i2)) { v2 = o1; i2 = oi1; }
            if ((o2 > v1) || (o2 == v1 && oi2 < i1)) { v2 = v1; i2 = i1; v1 = o2; i1 = oi2; }
            else if ((o2 > v2) || (o2 == v2 && oi2 < i2)) { v2 = o2; i2 = oi2; }
        }
        if (l15 == 0) {
            const int T = rt * 16 + l4 * 4 + j;
            tv_s[T][ty][0] = v1; tv_s[T][ty][1] = v2;
            ti_s[T][ty][0] = i1; ti_s[T][ty][1] = i2;
        }
    }
    __syncthreads();

    // cross-wave merge (one thread per token)
    if (tid < TM) {
        float v1 = -3.4e38f, v2 = -3.4e38f;
        int   i1 = 0x7fffffff, i2 = 0x7fffffff;
#pragma unroll
        for (int w = 0; w < 4; ++w)
#pragma unroll
            for (int q = 0; q < 2; ++q) {
                float val = tv_s[tid][w][q]; int vi = ti_s[tid][w][q];
                if ((val > v1) || (val == v1 && vi < i1)) { v2 = v1; i2 = i1; v1 = val; i1 = vi; }
                else if ((val > v2) || (val == v2 && vi < i2)) { v2 = val; i2 = vi; }
            }
        m_s[tid] = v1; gap_s[tid] = v1 - v2;
        i1_s[tid] = i1; i2_s[tid] = i2; kb_s[tid] = i1; sum_s[tid] = 0.f;
    }
    __syncthreads();

    // softmax: exp + per-token sum
#pragma unroll
    for (int rt = 0; rt < 2; ++rt)
#pragma unroll
    for (int j = 0; j < 4; ++j) {
        const int T = rt * 16 + l4 * 4 + j;
        const float m = m_s[T];
        float s = 0.f;
#pragma unroll
        for (int ct = 0; ct < 5; ++ct) {
            float e = expf(acc[rt][ct][j] - m);
            acc[rt][ct][j] = e;
            s += e;
        }
#pragma unroll
        for (int off = 1; off <= 8; off <<= 1) s += __shfl_xor(s, off);
        if (l15 == 0) atomicAdd(&sum_s[T], s);
    }
    __syncthreads();

    // avg_probs partials: l4-shuffle reduce then per-wave-exclusive plain adds
#pragma unroll
    for (int ct = 0; ct < 5; ++ct) {
        float tot = 0.f;
#pragma unroll
        for (int rt = 0; rt < 2; ++rt)
#pragma unroll
        for (int j = 0; j < 4; ++j) {
            const int T = rt * 16 + l4 * 4 + j;
            float v = acc[rt][ct][j] / sum_s[T];
            v += __shfl_xor(v, 16);
            v += __shfl_xor(v, 32);
            tot += v;
        }
        if (l4 == 0) avg_s[ty * 80 + ct * 16 + l15] += tot;
    }

    // f64 re-verify close argmaxes (bf16x3 logit err ~3e-4 << 0.05 gap)
    for (int t8 = 0; t8 < 8; ++t8) {
        const int T = ty * 8 + t8;
        if (gap_s[T] <= 0.05f) {
            const int i1 = i1_s[T], i2 = i2_s[T];
            const float* xr = x + (size_t)(n0 + T) * DIM;
            const float* w1 = W + (size_t)(g * NUM_VARS + i1) * DIM;
            const float* w2 = W + (size_t)(g * NUM_VARS + i2) * DIM;
            double d1 = 0.0, d2 = 0.0;
            for (int k = lane; k < DIM; k += 64) {
                double xv = (double)xr[k];
                d1 += xv * (double)w1[k];
                d2 += xv * (double)w2[k];
            }
#pragma unroll
            for (int off = 1; off <= 32; off <<= 1) {
                d1 += __shfl_xor(d1, off);
                d2 += __shfl_xor(d2, off);
            }
            d1 += (double)bias[g * NUM_VARS + i1];
            d2 += (double)bias[g * NUM_VARS + i2];
            if (lane == 0)
                kb_s[T] = (d2 > d1 || (d2 == d1 && i2 < i1)) ? i2 : i1;
        }
    }
    __syncthreads();

    // codebook gather -> out (coalesced float4)
#pragma unroll
    for (int i = 0; i < 4; ++i) {
        const int f = tid + i * BLOCK;
        const int T = f >> 5, p = f & 31;
        const int kb = kb_s[T];
        float4 cv = *(const float4*)(codebook +
                     (size_t)(g * NUM_VARS + kb) * VAR_DIM + p * 4);
        *(float4*)(out + (size_t)(n0 + T) * (GROUPS * VAR_DIM) + g * VAR_DIM + p * 4) = cv;
    }

    const float scale = 1.f / (float)NTOK;
    for (int i = tid; i < NUM_VARS; i += BLOCK)
        atomicAdd(&avg_out[g * NUM_VARS + i], avg_s[i] * scale);
}

// ---------------- fallback path (R6, proven): LDS-staged x ----------------
template <bool USE_WQ>
__global__ __launch_bounds__(BLOCK, 2)
void vq_mfma_kernel(const float* __restrict__ x,
                    const float* __restrict__ W,
                    const u16* __restrict__ Wpk,
                    const float* __restrict__ bias,
                    const float* __restrict__ codebook,
                    float* __restrict__ out,
                    float* __restrict__ avg_out) {
    __shared__ u16 xs_hi[TM][XP];
    __shared__ u16 xs_lo[TM][XP];
    __shared__ float avg_s[NUM_VARS];
    __shared__ float tv_s[TM][4][2];
    __shared__ int   ti_s[TM][4][2];
    __shared__ float m_s[TM], gap_s[TM], sum_s[TM];
    __shared__ int   i1_s[TM], i2_s[TM], kb_s[TM];

    const int tid  = threadIdx.x;
    const int lane = tid & 63;
    const int ty   = tid >> 6;
    const int l15  = lane & 15;
    const int l4   = lane >> 4;
    const int g    = blockIdx.x & 1;
    const int n0   = (blockIdx.x >> 1) * TM;

    for (int i = tid; i < NUM_VARS; i += BLOCK) avg_s[i] = 0.f;

    const f32x4 zf = {0.f, 0.f, 0.f, 0.f};
    f32x4 acc[2][5];
#pragma unroll
    for (int rt = 0; rt < 2; ++rt)
#pragma unroll
        for (int ct = 0; ct < 5; ++ct) acc[rt][ct] = zf;

    const int vw = g * NUM_VARS + ty * 80;

    for (int c = 0; c < DIM / KCH; ++c) {
        __syncthreads();
        {
            const int t  = tid >> 3;
            const int kb = (tid & 7) * 4;
            const float* xp = x + (size_t)(n0 + t) * DIM + c * KCH;
#pragma unroll
            for (int i = 0; i < 8; ++i) {
                const int k = kb + i * 32;
                float4 v = *(const float4*)(xp + k);
                u16x4 hv, lv; u16 h, l;
                split2(v.x, h, l); hv[0] = h; lv[0] = l;
                split2(v.y, h, l); hv[1] = h; lv[1] = l;
                split2(v.z, h, l); hv[2] = h; lv[2] = l;
                split2(v.w, h, l); hv[3] = h; lv[3] = l;
                *(u16x4*)&xs_hi[t][k] = hv;
                *(u16x4*)&xs_lo[t][k] = lv;
            }
        }
        __syncthreads();
#pragma unroll
        for (int ks = 0; ks < KCH / 32; ++ks) {
            const int ko = ks * 32 + 8 * l4;
            bf16x8 ah0 = *(const bf16x8*)&xs_hi[l15][ko];
            bf16x8 al0 = *(const bf16x8*)&xs_lo[l15][ko];
            bf16x8 ah1 = *(const bf16x8*)&xs_hi[16 + l15][ko];
            bf16x8 al1 = *(const bf16x8*)&xs_lo[16 + l15][ko];
            const int ksg = c * (KCH / 32) + ks;
#pragma unroll
            for (int ct = 0; ct < 5; ++ct) {
                bf16x8 bh, bl;
                if (USE_WQ) {
                    const int v16g = g * (NUM_VARS / 16) + ty * 5 + ct;
                    const u16* wp = Wpk + (size_t)((v16g * NKS + ksg) * 2) * 512 + lane * 8;
                    bh = *(const bf16x8*)wp;
                    bl = *(const bf16x8*)(wp + 512);
                } else {
                    const int kg = ksg * 32 + 8 * l4;
                    const float* wp = W + (size_t)(vw + ct * 16 + l15) * DIM + kg;
                    float4 wa = *(const float4*)wp;
                    float4 wb = *(const float4*)(wp + 4);
                    u16 h, l;
                    split2(wa.x, h, l); bh[0] = (short)h; bl[0] = (short)l;
                    split2(wa.y, h, l); bh[1] = (short)h; bl[1] = (short)l;
                    split2(wa.z, h, l); bh[2] = (short)h; bl[2] = (short)l;
                    split2(wa.w, h, l); bh[3] = (short)h; bl[3] = (short)l;
                    split2(wb.x, h, l); bh[4] = (short)h; bl[4] = (short)l;
                    split2(wb.y, h, l); bh[5] = (short)h; bl[5] = (short)l;
                    split2(wb.z, h, l); bh[6] = (short)h; bl[6] = (short)l;
                    split2(wb.w, h, l); bh[7] = (short)h; bl[7] = (short)l;
                }
                acc[0][ct] = __builtin_amdgcn_mfma_f32_16x16x32_bf16(ah0, bh, acc[0][ct], 0, 0, 0);
                acc[0][ct] = __builtin_amdgcn_mfma_f32_16x16x32_bf16(ah0, bl, acc[0][ct], 0, 0, 0);
                acc[0][ct] = __builtin_amdgcn_mfma_f32_16x16x32_bf16(al0, bh, acc[0][ct], 0, 0, 0);
                acc[1][ct] = __builtin_amdgcn_mfma_f32_16x16x32_bf16(ah1, bh, acc[1][ct], 0, 0, 0);
                acc[1][ct] = __builtin_amdgcn_mfma_f32_16x16x32_bf16(ah1, bl, acc[1][ct], 0, 0, 0);
                acc[1][ct] = __builtin_amdgcn_mfma_f32_16x16x32_bf16(al1, bh, acc[1][ct], 0, 0, 0);
            }
        }
    }

#pragma unroll
    for (int ct = 0; ct < 5; ++ct) {
        float bv = bias[vw + ct * 16 + l15];
#pragma unroll
        for (int rt = 0; rt < 2; ++rt)
#pragma unroll
            for (int j = 0; j < 4; ++j) acc[rt][ct][j] += bv;
    }

#pragma unroll
    for (int rt = 0; rt < 2; ++rt)
#pragma unroll
    for (int j = 0; j < 4; ++j) {
        float v1 = -3.4e38f, v2 = -3.4e38f;
        int   i1 = 0x7fffffff, i2 = 0x7fffffff;
#pragma unroll
        for (int ct = 0; ct < 5; ++ct) {
            float val = acc[rt][ct][j];
            int   vi  = ty * 80 + ct * 16 + l15;
            if ((val > v1) || (val == v1 && vi < i1)) { v2 = v1; i2 = i1; v1 = val; i1 = vi; }
            else if ((val > v2) || (val == v2 && vi < i2)) { v2 = val; i2 = vi; }
        }
#pragma unroll
        for (int off = 1; off <= 8; off <<= 1) {
            float o1 = __shfl_xor(v1, off); int oi1 = __shfl_xor(i1, off);
            float o2 = __shfl_xor(v2, off); int oi2 = __shfl_xor(i2, off);
            if ((o1 > v1) || (o1 == v1 && oi1 < i1)) { v2 = v1; i2 = i1; v1 = o1; i1 = oi1; }
            else if ((o1 > v2) || (o1 == v2 && oi1 < i2)) { v2 = o1; i2 = oi1; }
            if ((o2 > v1) || (o2 == v1 && oi2 < i1)) { v2 = v1; i2 = i1; v1 = o2; i1 = oi2; }
            else if ((o2 > v2) || (o2 == v2 && oi2 < i2)) { v2 = o2; i2 = oi2; }
        }
        if (l15 == 0) {
            const int T = rt * 16 + l4 * 4 + j;
            tv_s[T][ty][0] = v1; tv_s[T][ty][1] = v2;
            ti_s[T][ty][0] = i1; ti_s[T][ty][1] = i2;
        }
    }
    __syncthreads();

    if (tid < TM) {
        float v1 = -3.4e38f, v2 = -3.4e38f;
        int   i1 = 0x7fffffff, i2 = 0x7fffffff;
#pragma unroll
        for (int w = 0; w < 4; ++w)
#pragma unroll
            for (int q = 0; q < 2; ++q) {
                float val = tv_s[tid][w][q]; int vi = ti_s[tid][w][q];
                if ((val > v1) || (val == v1 && vi < i1)) { v2 = v1; i2 = i1; v1 = val; i1 = vi; }
                else if ((val > v2) || (val == v2 && vi < i2)) { v2 = val; i2 = vi; }
            }
        m_s[tid] = v1; gap_s[tid] = v1 - v2;
        i1_s[tid] = i1; i2_s[tid] = i2; kb_s[tid] = i1; sum_s[tid] = 0.f;
    }
    __syncthreads();

#pragma unroll
    for (int rt = 0; rt < 2; ++rt)
#pragma unroll
    for (int j = 0; j < 4; ++j) {
        const int T = rt * 16 + l4 * 4 + j;
        const float m = m_s[T];
        float s = 0.f;
#pragma unroll
        for (int ct = 0; ct < 5; ++ct) {
            float e = expf(acc[rt][ct][j] - m);
            acc[rt][ct][j] = e;
            s += e;
        }
#pragma unroll
        for (int off = 1; off <= 8; off <<= 1) s += __shfl_xor(s, off);
        if (l15 == 0) atomicAdd(&sum_s[T], s);
    }
    __syncthreads();

#pragma unroll
    for (int ct = 0; ct < 5; ++ct) {
        float tot = 0.f;
#pragma unroll
        for (int rt = 0; rt < 2; ++rt)
#pragma unroll
        for (int j = 0; j < 4; ++j) {
            const int T = rt * 16 + l4 * 4 + j;
            float v = acc[rt][ct][j] / sum_s[T];
            v += __shfl_xor(v, 16);
            v += __shfl_xor(v, 32);
            tot += v;
        }
        if (l4 == 0) avg_s[ty * 80 + ct * 16 + l15] += tot;
    }

    for (int t8 = 0; t8 < 8; ++t8) {
        const int T = ty * 8 + t8;
        if (gap_s[T] <= 0.05f) {
            const int i1 = i1_s[T], i2 = i2_s[T];
            const float* xr = x + (size_t)(n0 + T) * DIM;
            const float* w1 = W + (size_t)(g * NUM_VARS + i1) * DIM;
            const float* w2 = W + (size_t)(g * NUM_VARS + i2) * DIM;
            double d1 = 0.0, d2 = 0.0;
            for (int k = lane; k < DIM; k += 64) {
                double xv = (double)xr[k];
                d1 += xv * (double)w1[k];
                d2 += xv * (double)w2[k];
            }
#pragma unroll
            for (int off = 1; off <= 32; off <<= 1) {
                d1 += __shfl_xor(d1, off);
                d2 += __shfl_xor(d2, off);
            }
            d1 += (double)bias[g * NUM_VARS + i1];
            d2 += (double)bias[g * NUM_VARS + i2];
            if (lane == 0)
                kb_s[T] = (d2 > d1 || (d2 == d1 && i2 < i1)) ? i2 : i1;
        }
    }
    __syncthreads();

#pragma unroll
    for (int i = 0; i < 4; ++i) {
        const int f = tid + i * BLOCK;
        const int T = f >> 5, p = f & 31;
        const int kb = kb_s[T];
        float4 cv = *(const float4*)(codebook +
                     (size_t)(g * NUM_VARS + kb) * VAR_DIM + p * 4);
        *(float4*)(out + (size_t)(n0 + T) * (GROUPS * VAR_DIM) + g * VAR_DIM + p * 4) = cv;
    }

    const float scale = 1.f / (float)NTOK;
    for (int i = tid; i < NUM_VARS; i += BLOCK)
        atomicAdd(&avg_out[g * NUM_VARS + i], avg_s[i] * scale);
}

extern "C" void kernel_launch(void* const* d_in, const int* in_sizes, int n_in,
                              void* d_out, int out_size, void* d_ws, size_t ws_size,
                              hipStream_t stream) {
    const float* x  = (const float*)d_in[0];
    const float* W  = (const float*)d_in[1];
    const float* b  = (const float*)d_in[2];
    const float* cb = (const float*)d_in[3];
    float* out = (float*)d_out;
    float* avg = out + (size_t)NTOK * GROUPS * VAR_DIM;

    hipMemsetAsync(avg, 0, NVT * sizeof(float), stream);

    const size_t wpk_bytes = (size_t)NT16 * NKS * 2 * 512 * sizeof(u16);        // 1.31 MB
    const size_t xpk_bytes = (size_t)NTILE * NKS * 2 * 512 * sizeof(u16);       // 98.3 MB
    const size_t full_bytes = wpk_bytes + xpk_bytes;                            // 99.7 MB

    if (ws_size >= full_bytes) {
        u16* Wpk = (u16*)d_ws;
        u16* xpk = (u16*)((char*)d_ws + wpk_bytes);
        pack_w_kernel<<<(NT16 * NKS * 64 * 8 + 255) / 256, 256, 0, stream>>>(W, Wpk);
        split_x_pack_kernel<<<(NTILE + 3) / 4, 256, 0, stream>>>(x, xpk);
        vq_mfma_reg_kernel<<<(NTOK / TM) * GROUPS, BLOCK, 0, stream>>>(
            x, W, xpk, Wpk, b, cb, out, avg);
    } else if (ws_size >= wpk_bytes) {
        u16* Wpk = (u16*)d_ws;
        pack_w_kernel<<<(NT16 * NKS * 64 * 8 + 255) / 256, 256, 0, stream>>>(W, Wpk);
        vq_mfma_kernel<true><<<(NTOK / TM) * GROUPS, BLOCK, 0, stream>>>(x, W, Wpk, b, cb, out, avg);
    } else {
        vq_mfma_kernel<false><<<(NTOK / TM) * GROUPS, BLOCK, 0, stream>>>(x, W, nullptr, b, cb, out, avg);
    }
}

// Round 9
// 200.570 us; speedup vs baseline: 20.0123x; 1.0191x over previous
//
#include <hip/hip_runtime.h>

#define GROUPS 2
#define NUM_VARS 320
#define NVT 640
#define DIM 512
#define VAR_DIM 128
#define NTOK 48000
#define TM 32            // (fallback path) tokens per block
#define TMF 64           // fast-path tokens per block (4 row-tiles)
#define BLOCK 256
#define KCH 256          // (fallback path) K-chunk staged in LDS
#define XP 264           // (fallback path) padded row stride (ushorts)
#define NT16 40          // total 16-var tiles (NVT/16)
#define NKS 16           // total 32-k slices (DIM/32)
#define NTILE (NTOK / 16)   // 3000 16-token tiles
#define TSTRIDE (NKS * 2 * 512)   // u16 elements per packed 16-token tile

typedef short bf16x8 __attribute__((ext_vector_type(8)));
typedef float f32x4  __attribute__((ext_vector_type(4)));
typedef unsigned short u16;
typedef u16 u16x4 __attribute__((ext_vector_type(4)));
typedef u16 u16x8 __attribute__((ext_vector_type(8)));

__device__ inline u16 bf16_rne(float f) {
    unsigned u = __builtin_bit_cast(unsigned, f);
    return (u16)((u + 0x7fffu + ((u >> 16) & 1u)) >> 16);
}
__device__ inline void split2(float f, u16& h, u16& l) {
    h = bf16_rne(f);
    float fh = __builtin_bit_cast(float, (unsigned)h << 16);
    l = bf16_rne(f - fh);
}

// Pre-split W into bf16 hi/lo in MFMA-fragment order (validated R5-R8, absmax=0):
//   offset = ((v16*NKS+ks)*2+hilo)*512 + lane*8 + j
//   row = v16*16 + (lane&15), k = ks*32 + 8*(lane>>4) + j.
__global__ void pack_w_kernel(const float* __restrict__ W, u16* __restrict__ Wpk) {
    int idx = blockIdx.x * blockDim.x + threadIdx.x;
    if (idx >= NT16 * NKS * 64 * 8) return;
    int j    = idx & 7;
    int lane = (idx >> 3) & 63;
    int ks   = (idx >> 9) & 15;
    int v16  = idx >> 13;
    int row  = v16 * 16 + (lane & 15);
    int k    = ks * 32 + 8 * (lane >> 4) + j;
    u16 h, l;
    split2(W[(size_t)row * DIM + k], h, l);
    size_t base = (size_t)((v16 * NKS + ks) * 2) * 512 + lane * 8 + j;
    Wpk[base]       = h;
    Wpk[base + 512] = l;
}

// Pre-split x into bf16 hi/lo in MFMA A-fragment order (validated R8, absmax=0):
//   xpk[tile][ks][hilo][512], token = tile*16 + (lane&15), k = ks*32+8*(lane>>4)+j
__global__ void split_x_pack_kernel(const float* __restrict__ x,
                                    u16* __restrict__ xpk) {
    const int gw   = (blockIdx.x * blockDim.x + threadIdx.x) >> 6;  // wave = tile
    const int lane = threadIdx.x & 63;
    if (gw >= NTILE) return;
    const int l15 = lane & 15, l4 = lane >> 4;
    const float* xr = x + (size_t)(gw * 16 + l15) * DIM + 8 * l4;
    u16* dst = xpk + (size_t)gw * TSTRIDE + lane * 8;
#pragma unroll 4
    for (int ks = 0; ks < NKS; ++ks) {
        float4 a = *(const float4*)(xr + ks * 32);
        float4 b = *(const float4*)(xr + ks * 32 + 4);
        u16x8 hv, lv; u16 h, l;
        split2(a.x, h, l); hv[0] = h; lv[0] = l;
        split2(a.y, h, l); hv[1] = h; lv[1] = l;
        split2(a.z, h, l); hv[2] = h; lv[2] = l;
        split2(a.w, h, l); hv[3] = h; lv[3] = l;
        split2(b.x, h, l); hv[4] = h; lv[4] = l;
        split2(b.y, h, l); hv[5] = h; lv[5] = l;
        split2(b.z, h, l); hv[6] = h; lv[6] = l;
        split2(b.w, h, l); hv[7] = h; lv[7] = l;
        *(u16x8*)(dst + ks * 1024)       = hv;
        *(u16x8*)(dst + ks * 1024 + 512) = lv;
    }
}

// ---------------- fast path: 64 tokens x one group per block ----------------
// R8 post-mortem: at 32 tokens/block every block re-streamed its group's whole
// Wpk (640 KB) from L2 -> 1.9 GB L2 B-traffic, 10KB loads per 150cyc MFMA per
// ks -> latency-bound at MfmaUtil 22%. 64 tokens/block: 60 MFMA (300cyc) per
// 18KB loads, half the total B traffic. acc = 4rt x 5ct x 4 = 80 f32 (AGPRs).
__global__ __launch_bounds__(BLOCK, 2)
void vq_mfma_reg_kernel(const float* __restrict__ x,
                        const float* __restrict__ W,
                        const u16* __restrict__ xpk,
                        const u16* __restrict__ Wpk,
                        const float* __restrict__ bias,
                        const float* __restrict__ codebook,
                        float* __restrict__ out,
                        float* __restrict__ avg_out) {
    __shared__ float avg_s[NUM_VARS];
    __shared__ float tv_s[TMF][4][2];
    __shared__ int   ti_s[TMF][4][2];
    __shared__ float m_s[TMF], gap_s[TMF], sum_s[TMF];
    __shared__ int   i1_s[TMF], i2_s[TMF], kb_s[TMF];

    const int tid  = threadIdx.x;
    const int lane = tid & 63;
    const int ty   = tid >> 6;
    const int l15  = lane & 15;
    const int l4   = lane >> 4;
    const int g    = blockIdx.x & 1;
    const int n0   = (blockIdx.x >> 1) * TMF;

    for (int i = tid; i < NUM_VARS; i += BLOCK) avg_s[i] = 0.f;

    const f32x4 zf = {0.f, 0.f, 0.f, 0.f};
    f32x4 acc[4][5];
#pragma unroll
    for (int rt = 0; rt < 4; ++rt)
#pragma unroll
        for (int ct = 0; ct < 5; ++ct) acc[rt][ct] = zf;

    const u16* xa = xpk + (size_t)((blockIdx.x >> 1) * 4) * TSTRIDE + lane * 8;
    const u16* wpk_b = Wpk + (size_t)(g * 20 + ty * 5) * TSTRIDE + lane * 8;

#pragma unroll 2
    for (int ks = 0; ks < NKS; ++ks) {
        bf16x8 ah[4], al[4];
#pragma unroll
        for (int rt = 0; rt < 4; ++rt) {
            ah[rt] = *(const bf16x8*)(xa + (size_t)rt * TSTRIDE + ks * 1024);
            al[rt] = *(const bf16x8*)(xa + (size_t)rt * TSTRIDE + ks * 1024 + 512);
        }
#pragma unroll
        for (int ct = 0; ct < 5; ++ct) {
            const u16* wp = wpk_b + (size_t)(ct * NKS + ks) * 2 * 512;
            bf16x8 bh = *(const bf16x8*)wp;
            bf16x8 bl = *(const bf16x8*)(wp + 512);
#pragma unroll
            for (int rt = 0; rt < 4; ++rt) {
                acc[rt][ct] = __builtin_amdgcn_mfma_f32_16x16x32_bf16(ah[rt], bh, acc[rt][ct], 0, 0, 0);
                acc[rt][ct] = __builtin_amdgcn_mfma_f32_16x16x32_bf16(ah[rt], bl, acc[rt][ct], 0, 0, 0);
                acc[rt][ct] = __builtin_amdgcn_mfma_f32_16x16x32_bf16(al[rt], bh, acc[rt][ct], 0, 0, 0);
            }
        }
    }

    // bias (zeros in harness; kept for generality)
#pragma unroll
    for (int ct = 0; ct < 5; ++ct) {
        float bv = bias[g * NUM_VARS + ty * 80 + ct * 16 + l15];
#pragma unroll
        for (int rt = 0; rt < 4; ++rt)
#pragma unroll
            for (int j = 0; j < 4; ++j) acc[rt][ct][j] += bv;
    }

    // per-token wave-local top-2 (16-lane butterfly)
#pragma unroll
    for (int rt = 0; rt < 4; ++rt)
#pragma unroll
    for (int j = 0; j < 4; ++j) {
        float v1 = -3.4e38f, v2 = -3.4e38f;
        int   i1 = 0x7fffffff, i2 = 0x7fffffff;
#pragma unroll
        for (int ct = 0; ct < 5; ++ct) {
            float val = acc[rt][ct][j];
            int   vi  = ty * 80 + ct * 16 + l15;
            if ((val > v1) || (val == v1 && vi < i1)) { v2 = v1; i2 = i1; v1 = val; i1 = vi; }
            else if ((val > v2) || (val == v2 && vi < i2)) { v2 = val; i2 = vi; }
        }
#pragma unroll
        for (int off = 1; off <= 8; off <<= 1) {
            float o1 = __shfl_xor(v1, off); int oi1 = __shfl_xor(i1, off);
            float o2 = __shfl_xor(v2, off); int oi2 = __shfl_xor(i2, off);
            if ((o1 > v1) || (o1 == v1 && oi1 < i1)) { v2 = v1; i2 = i1; v1 = o1; i1 = oi1; }
            else if ((o1 > v2) || (o1 == v2 && oi1 < i2)) { v2 = o1; i2 = oi1; }
            if ((o2 > v1) || (o2 == v1 && oi2 < i1)) { v2 = v1; i2 = i1; v1 = o2; i1 = oi2; }
            else if ((o2 > v2) || (o2 == v2 && oi2 < i2)) { v2 = o2; i2 = oi2; }
        }
        if (l15 == 0) {
            const int T = rt * 16 + l4 * 4 + j;
            tv_s[T][ty][0] = v1; tv_s[T][ty][1] = v2;
            ti_s[T][ty][0] = i1; ti_s[T][ty][1] = i2;
        }
    }
    __syncthreads();

    // cross-wave merge (one thread per token)
    if (tid < TMF) {
        float v1 = -3.4e38f, v2 = -3.4e38f;
        int   i1 = 0x7fffffff, i2 = 0x7fffffff;
#pragma unroll
        for (int w = 0; w < 4; ++w)
#pragma unroll
            for (int q = 0; q < 2; ++q) {
                float val = tv_s[tid][w][q]; int vi = ti_s[tid][w][q];
                if ((val > v1) || (val == v1 && vi < i1)) { v2 = v1; i2 = i1; v1 = val; i1 = vi; }
                else if ((val > v2) || (val == v2 && vi < i2)) { v2 = val; i2 = vi; }
            }
        m_s[tid] = v1; gap_s[tid] = v1 - v2;
        i1_s[tid] = i1; i2_s[tid] = i2; kb_s[tid] = i1; sum_s[tid] = 0.f;
    }
    __syncthreads();

    // softmax: exp + per-token sum
#pragma unroll
    for (int rt = 0; rt < 4; ++rt)
#pragma unroll
    for (int j = 0; j < 4; ++j) {
        const int T = rt * 16 + l4 * 4 + j;
        const float m = m_s[T];
        float s = 0.f;
#pragma unroll
        for (int ct = 0; ct < 5; ++ct) {
            float e = expf(acc[rt][ct][j] - m);
            acc[rt][ct][j] = e;
            s += e;
        }
#pragma unroll
        for (int off = 1; off <= 8; off <<= 1) s += __shfl_xor(s, off);
        if (l15 == 0) atomicAdd(&sum_s[T], s);
    }
    __syncthreads();

    // avg_probs partials: l4-shuffle reduce then per-wave-exclusive plain adds
#pragma unroll
    for (int ct = 0; ct < 5; ++ct) {
        float tot = 0.f;
#pragma unroll
        for (int rt = 0; rt < 4; ++rt)
#pragma unroll
        for (int j = 0; j < 4; ++j) {
            const int T = rt * 16 + l4 * 4 + j;
            float v = acc[rt][ct][j] / sum_s[T];
            v += __shfl_xor(v, 16);
            v += __shfl_xor(v, 32);
            tot += v;
        }
        if (l4 == 0) avg_s[ty * 80 + ct * 16 + l15] += tot;
    }

    // f64 re-verify close argmaxes (bf16x3 logit err ~3e-4 << 0.05 gap)
    for (int t16 = 0; t16 < 16; ++t16) {
        const int T = ty * 16 + t16;
        if (gap_s[T] <= 0.05f) {
            const int i1 = i1_s[T], i2 = i2_s[T];
            const float* xr = x + (size_t)(n0 + T) * DIM;
            const float* w1 = W + (size_t)(g * NUM_VARS + i1) * DIM;
            const float* w2 = W + (size_t)(g * NUM_VARS + i2) * DIM;
            double d1 = 0.0, d2 = 0.0;
            for (int k = lane; k < DIM; k += 64) {
                double xv = (double)xr[k];
                d1 += xv * (double)w1[k];
                d2 += xv * (double)w2[k];
            }
#pragma unroll
            for (int off = 1; off <= 32; off <<= 1) {
                d1 += __shfl_xor(d1, off);
                d2 += __shfl_xor(d2, off);
            }
            d1 += (double)bias[g * NUM_VARS + i1];
            d2 += (double)bias[g * NUM_VARS + i2];
            if (lane == 0)
                kb_s[T] = (d2 > d1 || (d2 == d1 && i2 < i1)) ? i2 : i1;
        }
    }
    __syncthreads();

    // codebook gather -> out (coalesced float4): 64 tokens x 32 float4
#pragma unroll
    for (int i = 0; i < 8; ++i) {
        const int f = tid + i * BLOCK;
        const int T = f >> 5, p = f & 31;
        const int kb = kb_s[T];
        float4 cv = *(const float4*)(codebook +
                     (size_t)(g * NUM_VARS + kb) * VAR_DIM + p * 4);
        *(float4*)(out + (size_t)(n0 + T) * (GROUPS * VAR_DIM) + g * VAR_DIM + p * 4) = cv;
    }

    const float scale = 1.f / (float)NTOK;
    for (int i = tid; i < NUM_VARS; i += BLOCK)
        atomicAdd(&avg_out[g * NUM_VARS + i], avg_s[i] * scale);
}

// ---------------- fallback path (R6, proven): LDS-staged x ----------------
template <bool USE_WQ>
__global__ __launch_bounds__(BLOCK, 2)
void vq_mfma_kernel(const float* __restrict__ x,
                    const float* __restrict__ W,
                    const u16* __restrict__ Wpk,
                    const float* __restrict__ bias,
                    const float* __restrict__ codebook,
                    float* __restrict__ out,
                    float* __restrict__ avg_out) {
    __shared__ u16 xs_hi[TM][XP];
    __shared__ u16 xs_lo[TM][XP];
    __shared__ float avg_s[NUM_VARS];
    __shared__ float tv_s[TM][4][2];
    __shared__ int   ti_s[TM][4][2];
    __shared__ float m_s[TM], gap_s[TM], sum_s[TM];
    __shared__ int   i1_s[TM], i2_s[TM], kb_s[TM];

    const int tid  = threadIdx.x;
    const int lane = tid & 63;
    const int ty   = tid >> 6;
    const int l15  = lane & 15;
    const int l4   = lane >> 4;
    const int g    = blockIdx.x & 1;
    const int n0   = (blockIdx.x >> 1) * TM;

    for (int i = tid; i < NUM_VARS; i += BLOCK) avg_s[i] = 0.f;

    const f32x4 zf = {0.f, 0.f, 0.f, 0.f};
    f32x4 acc[2][5];
#pragma unroll
    for (int rt = 0; rt < 2; ++rt)
#pragma unroll
        for (int ct = 0; ct < 5; ++ct) acc[rt][ct] = zf;

    const int vw = g * NUM_VARS + ty * 80;

    for (int c = 0; c < DIM / KCH; ++c) {
        __syncthreads();
        {
            const int t  = tid >> 3;
            const int kb = (tid & 7) * 4;
            const float* xp = x + (size_t)(n0 + t) * DIM + c * KCH;
#pragma unroll
            for (int i = 0; i < 8; ++i) {
                const int k = kb + i * 32;
                float4 v = *(const float4*)(xp + k);
                u16x4 hv, lv; u16 h, l;
                split2(v.x, h, l); hv[0] = h; lv[0] = l;
                split2(v.y, h, l); hv[1] = h; lv[1] = l;
                split2(v.z, h, l); hv[2] = h; lv[2] = l;
                split2(v.w, h, l); hv[3] = h; lv[3] = l;
                *(u16x4*)&xs_hi[t][k] = hv;
                *(u16x4*)&xs_lo[t][k] = lv;
            }
        }
        __syncthreads();
#pragma unroll
        for (int ks = 0; ks < KCH / 32; ++ks) {
            const int ko = ks * 32 + 8 * l4;
            bf16x8 ah0 = *(const bf16x8*)&xs_hi[l15][ko];
            bf16x8 al0 = *(const bf16x8*)&xs_lo[l15][ko];
            bf16x8 ah1 = *(const bf16x8*)&xs_hi[16 + l15][ko];
            bf16x8 al1 = *(const bf16x8*)&xs_lo[16 + l15][ko];
            const int ksg = c * (KCH / 32) + ks;
#pragma unroll
            for (int ct = 0; ct < 5; ++ct) {
                bf16x8 bh, bl;
                if (USE_WQ) {
                    const int v16g = g * (NUM_VARS / 16) + ty * 5 + ct;
                    const u16* wp = Wpk + (size_t)((v16g * NKS + ksg) * 2) * 512 + lane * 8;
                    bh = *(const bf16x8*)wp;
                    bl = *(const bf16x8*)(wp + 512);
                } else {
                    const int kg = ksg * 32 + 8 * l4;
                    const float* wp = W + (size_t)(vw + ct * 16 + l15) * DIM + kg;
                    float4 wa = *(const float4*)wp;
                    float4 wb = *(const float4*)(wp + 4);
                    u16 h, l;
                    split2(wa.x, h, l); bh[0] = (short)h; bl[0] = (short)l;
                    split2(wa.y, h, l); bh[1] = (short)h; bl[1] = (short)l;
                    split2(wa.z, h, l); bh[2] = (short)h; bl[2] = (short)l;
                    split2(wa.w, h, l); bh[3] = (short)h; bl[3] = (short)l;
                    split2(wb.x, h, l); bh[4] = (short)h; bl[4] = (short)l;
                    split2(wb.y, h, l); bh[5] = (short)h; bl[5] = (short)l;
                    split2(wb.z, h, l); bh[6] = (short)h; bl[6] = (short)l;
                    split2(wb.w, h, l); bh[7] = (short)h; bl[7] = (short)l;
                }
                acc[0][ct] = __builtin_amdgcn_mfma_f32_16x16x32_bf16(ah0, bh, acc[0][ct], 0, 0, 0);
                acc[0][ct] = __builtin_amdgcn_mfma_f32_16x16x32_bf16(ah0, bl, acc[0][ct], 0, 0, 0);
                acc[0][ct] = __builtin_amdgcn_mfma_f32_16x16x32_bf16(al0, bh, acc[0][ct], 0, 0, 0);
                acc[1][ct] = __builtin_amdgcn_mfma_f32_16x16x32_bf16(ah1, bh, acc[1][ct], 0, 0, 0);
                acc[1][ct] = __builtin_amdgcn_mfma_f32_16x16x32_bf16(ah1, bl, acc[1][ct], 0, 0, 0);
                acc[1][ct] = __builtin_amdgcn_mfma_f32_16x16x32_bf16(al1, bh, acc[1][ct], 0, 0, 0);
            }
        }
    }

#pragma unroll
    for (int ct = 0; ct < 5; ++ct) {
        float bv = bias[vw + ct * 16 + l15];
#pragma unroll
        for (int rt = 0; rt < 2; ++rt)
#pragma unroll
            for (int j = 0; j < 4; ++j) acc[rt][ct][j] += bv;
    }

#pragma unroll
    for (int rt = 0; rt < 2; ++rt)
#pragma unroll
    for (int j = 0; j < 4; ++j) {
        float v1 = -3.4e38f, v2 = -3.4e38f;
        int   i1 = 0x7fffffff, i2 = 0x7fffffff;
#pragma unroll
        for (int ct = 0; ct < 5; ++ct) {
            float val = acc[rt][ct][j];
            int   vi  = ty * 80 + ct * 16 + l15;
            if ((val > v1) || (val == v1 && vi < i1)) { v2 = v1; i2 = i1; v1 = val; i1 = vi; }
            else if ((val > v2) || (val == v2 && vi < i2)) { v2 = val; i2 = vi; }
        }
#pragma unroll
        for (int off = 1; off <= 8; off <<= 1) {
            float o1 = __shfl_xor(v1, off); int oi1 = __shfl_xor(i1, off);
            float o2 = __shfl_xor(v2, off); int oi2 = __shfl_xor(i2, off);
            if ((o1 > v1) || (o1 == v1 && oi1 < i1)) { v2 = v1; i2 = i1; v1 = o1; i1 = oi1; }
            else if ((o1 > v2) || (o1 == v2 && oi1 < i2)) { v2 = o1; i2 = oi1; }
            if ((o2 > v1) || (o2 == v1 && oi2 < i1)) { v2 = v1; i2 = i1; v1 = o2; i1 = oi2; }
            else if ((o2 > v2) || (o2 == v2 && oi2 < i2)) { v2 = o2; i2 = oi2; }
        }
        if (l15 == 0) {
            const int T = rt * 16 + l4 * 4 + j;
            tv_s[T][ty][0] = v1; tv_s[T][ty][1] = v2;
            ti_s[T][ty][0] = i1; ti_s[T][ty][1] = i2;
        }
    }
    __syncthreads();

    if (tid < TM) {
        float v1 = -3.4e38f, v2 = -3.4e38f;
        int   i1 = 0x7fffffff, i2 = 0x7fffffff;
#pragma unroll
        for (int w = 0; w < 4; ++w)
#pragma unroll
            for (int q = 0; q < 2; ++q) {
                float val = tv_s[tid][w][q]; int vi = ti_s[tid][w][q];
                if ((val > v1) || (val == v1 && vi < i1)) { v2 = v1; i2 = i1; v1 = val; i1 = vi; }
                else if ((val > v2) || (val == v2 && vi < i2)) { v2 = val; i2 = vi; }
            }
        m_s[tid] = v1; gap_s[tid] = v1 - v2;
        i1_s[tid] = i1; i2_s[tid] = i2; kb_s[tid] = i1; sum_s[tid] = 0.f;
    }
    __syncthreads();

#pragma unroll
    for (int rt = 0; rt < 2; ++rt)
#pragma unroll
    for (int j = 0; j < 4; ++j) {
        const int T = rt * 16 + l4 * 4 + j;
        const float m = m_s[T];
        float s = 0.f;
#pragma unroll
        for (int ct = 0; ct < 5; ++ct) {
            float e = expf(acc[rt][ct][j] - m);
            acc[rt][ct][j] = e;
            s += e;
        }
#pragma unroll
        for (int off = 1; off <= 8; off <<= 1) s += __shfl_xor(s, off);
        if (l15 == 0) atomicAdd(&sum_s[T], s);
    }
    __syncthreads();

#pragma unroll
    for (int ct = 0; ct < 5; ++ct) {
        float tot = 0.f;
#pragma unroll
        for (int rt = 0; rt < 2; ++rt)
#pragma unroll
        for (int j = 0; j < 4; ++j) {
            const int T = rt * 16 + l4 * 4 + j;
            float v = acc[rt][ct][j] / sum_s[T];
            v += __shfl_xor(v, 16);
            v += __shfl_xor(v, 32);
            tot += v;
        }
        if (l4 == 0) avg_s[ty * 80 + ct * 16 + l15] += tot;
    }

    for (int t8 = 0; t8 < 8; ++t8) {
        const int T = ty * 8 + t8;
        if (gap_s[T] <= 0.05f) {
            const int i1 = i1_s[T], i2 = i2_s[T];
            const float* xr = x + (size_t)(n0 + T) * DIM;
            const float* w1 = W + (size_t)(g * NUM_VARS + i1) * DIM;
            const float* w2 = W + (size_t)(g * NUM_VARS + i2) * DIM;
            double d1 = 0.0, d2 = 0.0;
            for (int k = lane; k < DIM; k += 64) {
                double xv = (double)xr[k];
                d1 += xv * (double)w1[k];
                d2 += xv * (double)w2[k];
            }
#pragma unroll
            for (int off = 1; off <= 32; off <<= 1) {
                d1 += __shfl_xor(d1, off);
                d2 += __shfl_xor(d2, off);
            }
            d1 += (double)bias[g * NUM_VARS + i1];
            d2 += (double)bias[g * NUM_VARS + i2];
            if (lane == 0)
                kb_s[T] = (d2 > d1 || (d2 == d1 && i2 < i1)) ? i2 : i1;
        }
    }
    __syncthreads();

#pragma unroll
    for (int i = 0; i < 4; ++i) {
        const int f = tid + i * BLOCK;
        const int T = f >> 5, p = f & 31;
        const int kb = kb_s[T];
        float4 cv = *(const float4*)(codebook +
                     (size_t)(g * NUM_VARS + kb) * VAR_DIM + p * 4);
        *(float4*)(out + (size_t)(n0 + T) * (GROUPS * VAR_DIM) + g * VAR_DIM + p * 4) = cv;
    }

    const float scale = 1.f / (float)NTOK;
    for (int i = tid; i < NUM_VARS; i += BLOCK)
        atomicAdd(&avg_out[g * NUM_VARS + i], avg_s[i] * scale);
}

extern "C" void kernel_launch(void* const* d_in, const int* in_sizes, int n_in,
                              void* d_out, int out_size, void* d_ws, size_t ws_size,
                              hipStream_t stream) {
    const float* x  = (const float*)d_in[0];
    const float* W  = (const float*)d_in[1];
    const float* b  = (const float*)d_in[2];
    const float* cb = (const float*)d_in[3];
    float* out = (float*)d_out;
    float* avg = out + (size_t)NTOK * GROUPS * VAR_DIM;

    hipMemsetAsync(avg, 0, NVT * sizeof(float), stream);

    const size_t wpk_bytes = (size_t)NT16 * NKS * 2 * 512 * sizeof(u16);        // 1.31 MB
    const size_t xpk_bytes = (size_t)NTILE * NKS * 2 * 512 * sizeof(u16);       // 98.3 MB
    const size_t full_bytes = wpk_bytes + xpk_bytes;                            // 99.7 MB

    if (ws_size >= full_bytes) {
        u16* Wpk = (u16*)d_ws;
        u16* xpk = (u16*)((char*)d_ws + wpk_bytes);
        pack_w_kernel<<<(NT16 * NKS * 64 * 8 + 255) / 256, 256, 0, stream>>>(W, Wpk);
        split_x_pack_kernel<<<(NTILE + 3) / 4, 256, 0, stream>>>(x, xpk);
        vq_mfma_reg_kernel<<<(NTOK / TMF) * GROUPS, BLOCK, 0, stream>>>(
            x, W, xpk, Wpk, b, cb, out, avg);
    } else if (ws_size >= wpk_bytes) {
        u16* Wpk = (u16*)d_ws;
        pack_w_kernel<<<(NT16 * NKS * 64 * 8 + 255) / 256, 256, 0, stream>>>(W, Wpk);
        vq_mfma_kernel<true><<<(NTOK / TM) * GROUPS, BLOCK, 0, stream>>>(x, W, Wpk, b, cb, out, avg);
    } else {
        vq_mfma_kernel<false><<<(NTOK / TM) * GROUPS, BLOCK, 0, stream>>>(x, W, nullptr, b, cb, out, avg);
    }
}